// Round 1
// baseline (410.282 us; speedup 1.0000x reference)
//
#include <hip/hip_runtime.h>
#include <cstdint>

#define BB 4
#define NN 4096
#define CC 256

typedef __attribute__((ext_vector_type(8))) short bf16x8;
typedef __attribute__((ext_vector_type(4))) short bf16x4;
typedef __attribute__((ext_vector_type(4))) float f32x4;

#define MFMA(a, b, c) __builtin_amdgcn_mfma_f32_16x16x32_bf16((a), (b), (c), 0, 0, 0)

__device__ __forceinline__ unsigned short f2bf(float f) {
  union { float f; unsigned u; } v; v.f = f;
  unsigned r = v.u + 0x7fffu + ((v.u >> 16) & 1u);
  return (unsigned short)(r >> 16);
}
__device__ __forceinline__ float bf2f(unsigned short h) {
  union { unsigned u; float f; } v; v.u = ((unsigned)h) << 16;
  return v.f;
}

typedef __attribute__((address_space(3))) unsigned int lds_u32;
typedef __attribute__((address_space(1))) unsigned int glb_u32;

// async global->LDS, 16B per lane; LDS dest = wave-uniform base + lane*16
__device__ __forceinline__ void async_cp16(const void* g, void* l) {
  __builtin_amdgcn_global_load_lds((const glb_u32*)g,
                                   (lds_u32*)(unsigned)(unsigned long long)l,
                                   16, 0, 0);
}

__device__ __forceinline__ f32x4 red16(f32x4 v) {
  #pragma unroll
  for (int m = 1; m < 16; m <<= 1) {
    v.x += __shfl_xor(v.x, m, 64);
    v.y += __shfl_xor(v.y, m, 64);
    v.z += __shfl_xor(v.z, m, 64);
    v.w += __shfl_xor(v.w, m, 64);
  }
  return v;
}

// ---------------- W transpose: Wt[z][d][c] = W_z[c][d] as bf16 ----------------
__global__ __launch_bounds__(256) void transpose_w(const float* __restrict__ Wq,
                                                   const float* __restrict__ Wk,
                                                   const float* __restrict__ Wv,
                                                   unsigned short* __restrict__ Wt) {
  __shared__ float sT[64 * 65];
  int blk = blockIdx.x;            // 48 = 3 * 16
  int z = blk / 16, tl = blk % 16;
  int c0 = (tl >> 2) * 64, d0 = (tl & 3) * 64;
  const float* W = (z == 0) ? Wq : ((z == 1) ? Wk : Wv);
  #pragma unroll
  for (int i = 0; i < 16; ++i) {
    int e = i * 256 + threadIdx.x;
    int c = e >> 6, d = e & 63;
    sT[c * 65 + d] = W[(size_t)(c0 + c) * CC + d0 + d];
  }
  __syncthreads();
  #pragma unroll
  for (int i = 0; i < 16; ++i) {
    int e = i * 256 + threadIdx.x;
    int d = e >> 6, c = e & 63;
    Wt[(size_t)z * 65536 + (size_t)(d0 + d) * CC + c0 + c] = f2bf(sT[c * 65 + d]);
  }
}

// ---------------- instance-norm stats ----------------
__global__ __launch_bounds__(256) void stats_partial(const float* __restrict__ content,
                                                     const float* __restrict__ style,
                                                     float* __restrict__ sums) {
  int blk = blockIdx.x;                 // 256 blocks
  int t = blk >> 7, b = (blk >> 5) & 3, chunk = blk & 31;
  const float* X = t ? style : content;
  int c = threadIdx.x;
  const float* base = X + ((size_t)b * NN + (size_t)chunk * 128) * CC + c;
  float s = 0.f, ss = 0.f;
  #pragma unroll 4
  for (int r = 0; r < 128; ++r) {
    float x = base[(size_t)r * CC];
    s += x; ss += x * x;
  }
  atomicAdd(&sums[((t * 2 + 0) * BB + b) * CC + c], s);
  atomicAdd(&sums[((t * 2 + 1) * BB + b) * CC + c], ss);
}

__global__ __launch_bounds__(256) void stats_finalize(const float* __restrict__ sums,
                                                      float* __restrict__ stats) {
  int i = blockIdx.x * 256 + threadIdx.x;   // 2048 = 2*B*C
  int t = i >> 10, bc = i & 1023;
  float s = sums[(t * 2 + 0) * 1024 + bc];
  float ss = sums[(t * 2 + 1) * 1024 + bc];
  float m = s * (1.0f / NN);
  float var = ss * (1.0f / NN) - m * m;
  stats[(t * 2 + 0) * 1024 + bc] = m;
  stats[(t * 2 + 1) * 1024 + bc] = rsqrtf(var + 1e-5f);
}

// ---------------- QKV: x(normed) @ W + b, then l2norm (Q,K) or V/V^2 transposed store ----------------
__global__ __launch_bounds__(256, 1) void qkv_kernel(
    const float* __restrict__ content, const float* __restrict__ style,
    const unsigned short* __restrict__ Wt,
    const float* __restrict__ bq, const float* __restrict__ bk, const float* __restrict__ bv,
    const float* __restrict__ stats,
    unsigned short* __restrict__ Qn, unsigned short* __restrict__ Kn,
    unsigned short* __restrict__ Vct) {
  __shared__ unsigned short sX[64 * 256];   // 32 KB, x-hat tile [row][c]
  __shared__ unsigned short sW[256 * 64];   // 32 KB, Wt chunk [d][k]
  __shared__ unsigned short sOT[256 * 64];  // 32 KB, V output transposed [d][row]
  __shared__ float sSq[64];

  int tid = threadIdx.x;
  int wid = tid >> 6, lane = tid & 63, quad = lane >> 4, l16 = lane & 15;
  int uwid = __builtin_amdgcn_readfirstlane(wid);
  int tileid = blockIdx.x;      // 0..255 over B*N/64
  int z = blockIdx.y;           // 0=Q 1=K 2=V
  int gr0 = tileid * 64;        // global row over B*N
  int b = gr0 >> 12;

  const float* X = (z == 0) ? content : style;
  int statt = (z == 0) ? 0 : 1;
  const float* mean = stats + ((statt * 2 + 0) * BB + b) * CC;
  const float* rstd = stats + ((statt * 2 + 1) * BB + b) * CC;
  bool donorm = (z < 2);

  if (tid < 64) sSq[tid] = 0.f;

  // stage x-hat tile (normalize + bf16)
  {
    int row = tid >> 2;
    int c0 = (tid & 3) * 64;
    const float* xr = X + (size_t)(gr0 + row) * CC;
    #pragma unroll
    for (int i = 0; i < 8; ++i) {
      int c = c0 + i * 8;
      bf16x8 hh;
      #pragma unroll
      for (int j = 0; j < 8; ++j) {
        float x = xr[c + j];
        if (donorm) x = (x - mean[c + j]) * rstd[c + j];
        hh[j] = (short)f2bf(x);
      }
      *(bf16x8*)(sX + row * 256 + c) = hh;
    }
  }

  f32x4 zero4 = {0.f, 0.f, 0.f, 0.f};
  f32x4 acc[4][4];
  #pragma unroll
  for (int i = 0; i < 4; ++i)
    #pragma unroll
    for (int j = 0; j < 4; ++j) acc[i][j] = zero4;

  int n0 = wid * 64;   // this wave's output-col base
  const unsigned short* wb = Wt + (size_t)z * 65536;

  for (int chn = 0; chn < 4; ++chn) {
    int kk0 = chn * 64;
    __syncthreads();
    #pragma unroll
    for (int it = 0; it < 8; ++it) {
      int g = it * 256 + wid * 64 + lane;
      int d = g >> 3, j = g & 7;
      async_cp16(wb + d * 256 + kk0 + j * 8,
                 (char*)sW + (size_t)(it * 256 + uwid * 64) * 16);
    }
    __syncthreads();
    #pragma unroll
    for (int ks = 0; ks < 2; ++ks) {
      bf16x8 a[4];
      #pragma unroll
      for (int mf = 0; mf < 4; ++mf)
        a[mf] = *(const bf16x8*)(sX + (mf * 16 + l16) * 256 + kk0 + ks * 32 + quad * 8);
      #pragma unroll
      for (int nf = 0; nf < 4; ++nf) {
        bf16x8 bw = *(const bf16x8*)(sW + (n0 + nf * 16 + l16) * 64 + ks * 32 + quad * 8);
        #pragma unroll
        for (int mf = 0; mf < 4; ++mf) acc[mf][nf] = MFMA(a[mf], bw, acc[mf][nf]);
      }
    }
  }

  // bias
  const float* bias = (z == 0) ? bq : ((z == 1) ? bk : bv);
  #pragma unroll
  for (int nf = 0; nf < 4; ++nf) {
    float bb_ = bias[n0 + nf * 16 + l16];
    #pragma unroll
    for (int mf = 0; mf < 4; ++mf) {
      acc[mf][nf].x += bb_; acc[mf][nf].y += bb_;
      acc[mf][nf].z += bb_; acc[mf][nf].w += bb_;
    }
  }

  if (z < 2) {
    // l2-normalize rows, store bf16
    #pragma unroll
    for (int mf = 0; mf < 4; ++mf) {
      f32x4 ss = zero4;
      #pragma unroll
      for (int nf = 0; nf < 4; ++nf) ss += acc[mf][nf] * acc[mf][nf];
      ss = red16(ss);
      if (l16 == 0) {
        int r0 = mf * 16 + quad * 4;
        atomicAdd(&sSq[r0 + 0], ss.x);
        atomicAdd(&sSq[r0 + 1], ss.y);
        atomicAdd(&sSq[r0 + 2], ss.z);
        atomicAdd(&sSq[r0 + 3], ss.w);
      }
    }
    __syncthreads();
    if (tid < 64) sSq[tid] = rsqrtf(sSq[tid] + 1e-12f);
    __syncthreads();
    unsigned short* O = (z == 0) ? Qn : Kn;
    #pragma unroll
    for (int mf = 0; mf < 4; ++mf) {
      int r0 = mf * 16 + quad * 4;
      float rn0 = sSq[r0], rn1 = sSq[r0 + 1], rn2 = sSq[r0 + 2], rn3 = sSq[r0 + 3];
      #pragma unroll
      for (int nf = 0; nf < 4; ++nf) {
        int col = n0 + nf * 16 + l16;
        O[(size_t)(gr0 + r0 + 0) * CC + col] = f2bf(acc[mf][nf].x * rn0);
        O[(size_t)(gr0 + r0 + 1) * CC + col] = f2bf(acc[mf][nf].y * rn1);
        O[(size_t)(gr0 + r0 + 2) * CC + col] = f2bf(acc[mf][nf].z * rn2);
        O[(size_t)(gr0 + r0 + 3) * CC + col] = f2bf(acc[mf][nf].w * rn3);
      }
    }
  } else {
    // V path: stage transposed [d][row], then write Vct[b][d][n] and Vct[b][256+d][n] = V^2
    #pragma unroll
    for (int mf = 0; mf < 4; ++mf) {
      int r0 = mf * 16 + quad * 4;
      #pragma unroll
      for (int nf = 0; nf < 4; ++nf) {
        int col = n0 + nf * 16 + l16;
        bf16x4 pk;
        pk[0] = (short)f2bf(acc[mf][nf].x);
        pk[1] = (short)f2bf(acc[mf][nf].y);
        pk[2] = (short)f2bf(acc[mf][nf].z);
        pk[3] = (short)f2bf(acc[mf][nf].w);
        *(bf16x4*)(sOT + col * 64 + r0) = pk;
      }
    }
    __syncthreads();
    int n_in_b = gr0 & (NN - 1);
    unsigned short* vrow  = Vct + ((size_t)(b * 512 + tid)) * NN + n_in_b;
    unsigned short* v2row = Vct + ((size_t)(b * 512 + 256 + tid)) * NN + n_in_b;
    #pragma unroll
    for (int i = 0; i < 8; ++i) {
      bf16x8 hv = *(const bf16x8*)(sOT + tid * 64 + i * 8);
      *(bf16x8*)(vrow + i * 8) = hv;
      bf16x8 h2;
      #pragma unroll
      for (int j = 0; j < 8; ++j) {
        float f = bf2f((unsigned short)hv[j]);
        h2[j] = (short)f2bf(f * f);
      }
      *(bf16x8*)(v2row + i * 8) = h2;
    }
  }
}

// ---------------- flash attention (no-max softmax; cosine logits in [-1,1]) ----------------
__global__ __launch_bounds__(256, 1) void flash_kernel(
    const unsigned short* __restrict__ Qn,
    const unsigned short* __restrict__ Kn,
    const unsigned short* __restrict__ Vct,     // [b][512][N], ch<256: V, ch>=256: V^2
    const float* __restrict__ content,
    const float* __restrict__ stats,
    float* __restrict__ out) {
  __shared__ unsigned short sK[64 * 256];    // 32 KB [key][ch]
  __shared__ unsigned short sVcT[512 * 64];  // 64 KB [ch][key]; epilogue reuse as float [256][64]
  __shared__ unsigned short sP[64 * 64];     // 8 KB  [q][key]
  __shared__ float sL[64];

  int tid = threadIdx.x;
  int wid = tid >> 6, lane = tid & 63, quad = lane >> 4, l16 = lane & 15;
  int uwid = __builtin_amdgcn_readfirstlane(wid);

  int id = blockIdx.x;                       // XCD-aware swizzle: batch b on XCDs {2b,2b+1}
  int b = (id >> 1) & 3;
  int tile = ((id >> 3) << 1) | (id & 1);
  int q0 = tile * 64;

  int sm = (wid & 1) * 32, sn = (wid >> 1) * 32;  // S-phase 32x32 wave tile
  int cw = wid * 128;                             // PV wave col base (over 512)

  if (tid < 64) sL[tid] = 0.f;

  // Q A-frags in registers: rows sm..sm+31, full K=256
  bf16x8 qf[2][8];
  #pragma unroll
  for (int mf = 0; mf < 2; ++mf) {
    int row = q0 + sm + mf * 16 + l16;
    const unsigned short* base = Qn + (((size_t)b * NN + row) << 8);
    #pragma unroll
    for (int kf = 0; kf < 8; ++kf)
      qf[mf][kf] = *(const bf16x8*)(base + kf * 32 + quad * 8);
  }

  f32x4 zero4 = {0.f, 0.f, 0.f, 0.f};
  f32x4 om[4][8];
  #pragma unroll
  for (int i = 0; i < 4; ++i)
    #pragma unroll
    for (int j = 0; j < 8; ++j) om[i][j] = zero4;
  f32x4 Lacc[2];
  Lacc[0] = zero4; Lacc[1] = zero4;

  const unsigned short* kb = Kn + (((size_t)b * NN) << 8);
  const unsigned short* vb = Vct + ((size_t)b * 512) * NN;

  for (int kt = 0; kt < 64; ++kt) {
    int k0 = kt * 64;
    __syncthreads();
    // stage K-tile [64][256]
    #pragma unroll
    for (int it = 0; it < 8; ++it) {
      int g = it * 256 + wid * 64 + lane;
      int key = g >> 5, j = g & 31;
      async_cp16(kb + (((size_t)(k0 + key)) << 8) + j * 8,
                 (char*)sK + (size_t)(it * 256 + uwid * 64) * 16);
    }
    // stage VcT tile [512][64]
    #pragma unroll
    for (int it = 0; it < 16; ++it) {
      int g = it * 256 + wid * 64 + lane;
      int ch = g >> 3, j = g & 7;
      async_cp16(vb + (size_t)ch * NN + k0 + j * 8,
                 (char*)sVcT + (size_t)(it * 256 + uwid * 64) * 16);
    }
    __syncthreads();

    // S = Q . K^T  (32x32 per wave, K=256)
    f32x4 s00 = zero4, s01 = zero4, s10 = zero4, s11 = zero4;
    #pragma unroll
    for (int kf = 0; kf < 8; ++kf) {
      bf16x8 b0 = *(const bf16x8*)(sK + (sn + l16) * 256 + kf * 32 + quad * 8);
      bf16x8 b1 = *(const bf16x8*)(sK + (sn + 16 + l16) * 256 + kf * 32 + quad * 8);
      s00 = MFMA(qf[0][kf], b0, s00);
      s10 = MFMA(qf[1][kf], b0, s10);
      s01 = MFMA(qf[0][kf], b1, s01);
      s11 = MFMA(qf[1][kf], b1, s11);
    }

    // P = exp(S); accumulate row-partials; write sP (bf16)
    #pragma unroll
    for (int mf = 0; mf < 2; ++mf) {
      f32x4 sa = mf ? s10 : s00;
      f32x4 sb = mf ? s11 : s01;
      f32x4 p0, p1;
      p0.x = __expf(sa.x); p0.y = __expf(sa.y); p0.z = __expf(sa.z); p0.w = __expf(sa.w);
      p1.x = __expf(sb.x); p1.y = __expf(sb.y); p1.z = __expf(sb.z); p1.w = __expf(sb.w);
      Lacc[mf] += p0 + p1;
      int row0 = sm + mf * 16 + quad * 4;
      sP[(row0 + 0) * 64 + sn + l16] = f2bf(p0.x);
      sP[(row0 + 1) * 64 + sn + l16] = f2bf(p0.y);
      sP[(row0 + 2) * 64 + sn + l16] = f2bf(p0.z);
      sP[(row0 + 3) * 64 + sn + l16] = f2bf(p0.w);
      sP[(row0 + 0) * 64 + sn + 16 + l16] = f2bf(p1.x);
      sP[(row0 + 1) * 64 + sn + 16 + l16] = f2bf(p1.y);
      sP[(row0 + 2) * 64 + sn + 16 + l16] = f2bf(p1.z);
      sP[(row0 + 3) * 64 + sn + 16 + l16] = f2bf(p1.w);
    }
    __syncthreads();

    // O += P @ [V, V^2]  (wave: 64 rows x 128 cols)
    #pragma unroll
    for (int kf2 = 0; kf2 < 2; ++kf2) {
      bf16x8 a[4];
      #pragma unroll
      for (int mf2 = 0; mf2 < 4; ++mf2)
        a[mf2] = *(const bf16x8*)(sP + (mf2 * 16 + l16) * 64 + kf2 * 32 + quad * 8);
      #pragma unroll
      for (int nf = 0; nf < 8; ++nf) {
        bf16x8 bv2 = *(const bf16x8*)(sVcT + (cw + nf * 16 + l16) * 64 + kf2 * 32 + quad * 8);
        #pragma unroll
        for (int mf2 = 0; mf2 < 4; ++mf2) om[mf2][nf] = MFMA(a[mf2], bv2, om[mf2][nf]);
      }
    }
  }

  // finalize softmax denominators
  #pragma unroll
  for (int mf = 0; mf < 2; ++mf) {
    f32x4 v = red16(Lacc[mf]);
    if (l16 == 0) {
      int row0 = sm + mf * 16 + quad * 4;
      atomicAdd(&sL[row0 + 0], v.x);
      atomicAdd(&sL[row0 + 1], v.y);
      atomicAdd(&sL[row0 + 2], v.z);
      atomicAdd(&sL[row0 + 3], v.w);
    }
  }
  __syncthreads();   // sL complete + all PV reads of sVcT done

  float* sM2T = (float*)sVcT;   // [256][64] fp32 second-moment numerators
  if (wid >= 2) {
    #pragma unroll
    for (int mf2 = 0; mf2 < 4; ++mf2)
      #pragma unroll
      for (int nf = 0; nf < 8; ++nf) {
        int ch = (wid - 2) * 128 + nf * 16 + l16;
        *(f32x4*)(sM2T + ch * 64 + mf2 * 16 + quad * 4) = om[mf2][nf];
      }
  }
  __syncthreads();

  if (wid < 2) {
    const float* meanc = stats + (0 * BB + b) * CC;     // content mean
    const float* rstdc = stats + (1 * BB + b) * CC;     // content rstd
    float linv[4][4];
    #pragma unroll
    for (int mf2 = 0; mf2 < 4; ++mf2)
      #pragma unroll
      for (int r = 0; r < 4; ++r)
        linv[mf2][r] = 1.0f / sL[mf2 * 16 + quad * 4 + r];
    #pragma unroll
    for (int nf = 0; nf < 8; ++nf) {
      int ch = cw + nf * 16 + l16;     // 0..255
      float mc = meanc[ch], rc = rstdc[ch];
      #pragma unroll
      for (int mf2 = 0; mf2 < 4; ++mf2) {
        f32x4 vv = *(const f32x4*)(sM2T + ch * 64 + mf2 * 16 + quad * 4);
        f32x4 ov = om[mf2][nf];
        #pragma unroll
        for (int r = 0; r < 4; ++r) {
          int row = mf2 * 16 + quad * 4 + r;
          float li = linv[mf2][r];
          float ovr = (r == 0) ? ov.x : (r == 1) ? ov.y : (r == 2) ? ov.z : ov.w;
          float vvr = (r == 0) ? vv.x : (r == 1) ? vv.y : (r == 2) ? vv.z : vv.w;
          float M = ovr * li;
          float E2 = vvr * li;
          float S2 = E2 - M * M;
          float S = (S2 > 0.f) ? sqrtf(S2) : 0.f;
          size_t gi = (((size_t)b * NN + q0 + row) << 8) + ch;
          float xh = (content[gi] - mc) * rc;
          out[gi] = S * xh + M;
        }
      }
    }
  }
}

// ---------------- launcher ----------------
extern "C" void kernel_launch(void* const* d_in, const int* in_sizes, int n_in,
                              void* d_out, int out_size, void* d_ws, size_t ws_size,
                              hipStream_t stream) {
  const float* content = (const float*)d_in[0];
  const float* style   = (const float*)d_in[1];
  const float* Wq = (const float*)d_in[2];
  const float* bq = (const float*)d_in[3];
  const float* Wk = (const float*)d_in[4];
  const float* bk = (const float*)d_in[5];
  const float* Wv = (const float*)d_in[6];
  const float* bv = (const float*)d_in[7];
  char* ws = (char*)d_ws;

  float* sums            = (float*)(ws + 0);                 // 16 KB
  float* stats           = (float*)(ws + 16384);             // 16 KB
  unsigned short* Wt     = (unsigned short*)(ws + 32768);    // 384 KB
  unsigned short* Qn     = (unsigned short*)(ws + 425984);   // 8 MB
  unsigned short* Kn     = (unsigned short*)(ws + 8814592);  // 8 MB
  unsigned short* Vct    = (unsigned short*)(ws + 17203200); // 16 MB
  float* outp = (float*)d_out;

  hipMemsetAsync(d_ws, 0, 16384, stream);
  hipLaunchKernelGGL(transpose_w, dim3(48), dim3(256), 0, stream, Wq, Wk, Wv, Wt);
  hipLaunchKernelGGL(stats_partial, dim3(256), dim3(256), 0, stream, content, style, sums);
  hipLaunchKernelGGL(stats_finalize, dim3(8), dim3(256), 0, stream, sums, stats);
  hipLaunchKernelGGL(qkv_kernel, dim3(256, 3), dim3(256), 0, stream,
                     content, style, Wt, bq, bk, bv, stats, Qn, Kn, Vct);
  hipLaunchKernelGGL(flash_kernel, dim3(256), dim3(256), 0, stream,
                     Qn, Kn, Vct, content, stats, outp);
}

// Round 2
// 292.680 us; speedup vs baseline: 1.4018x; 1.4018x over previous
//
#include <hip/hip_runtime.h>
#include <cstdint>

#define BB 4
#define NN 4096
#define CC 256

typedef __attribute__((ext_vector_type(8))) short bf16x8;
typedef __attribute__((ext_vector_type(4))) short bf16x4;
typedef __attribute__((ext_vector_type(4))) float f32x4;

#define MFMA(a, b, c) __builtin_amdgcn_mfma_f32_16x16x32_bf16((a), (b), (c), 0, 0, 0)

__device__ __forceinline__ unsigned short f2bf(float f) {
  union { float f; unsigned u; } v; v.f = f;
  unsigned r = v.u + 0x7fffu + ((v.u >> 16) & 1u);
  return (unsigned short)(r >> 16);
}
__device__ __forceinline__ float bf2f(unsigned short h) {
  union { unsigned u; float f; } v; v.u = ((unsigned)h) << 16;
  return v.f;
}

typedef __attribute__((address_space(3))) unsigned int lds_u32;
typedef __attribute__((address_space(1))) unsigned int glb_u32;

// async global->LDS, 16B per lane; LDS dest = wave-uniform base + lane*16
__device__ __forceinline__ void async_cp16(const void* g, void* l) {
  __builtin_amdgcn_global_load_lds((const glb_u32*)g,
                                   (lds_u32*)(unsigned)(unsigned long long)l,
                                   16, 0, 0);
}

// ---------------- W transpose: Wt[z][d][c] = W_z[c][d] as bf16 ----------------
__global__ __launch_bounds__(256) void transpose_w(const float* __restrict__ Wq,
                                                   const float* __restrict__ Wk,
                                                   const float* __restrict__ Wv,
                                                   unsigned short* __restrict__ Wt) {
  __shared__ float sT[64 * 65];
  int blk = blockIdx.x;            // 48 = 3 * 16
  int z = blk / 16, tl = blk % 16;
  int c0 = (tl >> 2) * 64, d0 = (tl & 3) * 64;
  const float* W = (z == 0) ? Wq : ((z == 1) ? Wk : Wv);
  #pragma unroll
  for (int i = 0; i < 16; ++i) {
    int e = i * 256 + threadIdx.x;
    int c = e >> 6, d = e & 63;
    sT[c * 65 + d] = W[(size_t)(c0 + c) * CC + d0 + d];
  }
  __syncthreads();
  #pragma unroll
  for (int i = 0; i < 16; ++i) {
    int e = i * 256 + threadIdx.x;
    int d = e >> 6, c = e & 63;
    Wt[(size_t)z * 65536 + (size_t)(d0 + d) * CC + c0 + c] = f2bf(sT[c * 65 + d]);
  }
}

// ---------------- instance-norm stats ----------------
__global__ __launch_bounds__(256) void stats_partial(const float* __restrict__ content,
                                                     const float* __restrict__ style,
                                                     float* __restrict__ sums) {
  int blk = blockIdx.x;                 // 256 blocks
  int t = blk >> 7, b = (blk >> 5) & 3, chunk = blk & 31;
  const float* X = t ? style : content;
  int c = threadIdx.x;
  const float* base = X + ((size_t)b * NN + (size_t)chunk * 128) * CC + c;
  float s = 0.f, ss = 0.f;
  #pragma unroll 4
  for (int r = 0; r < 128; ++r) {
    float x = base[(size_t)r * CC];
    s += x; ss += x * x;
  }
  atomicAdd(&sums[((t * 2 + 0) * BB + b) * CC + c], s);
  atomicAdd(&sums[((t * 2 + 1) * BB + b) * CC + c], ss);
}

__global__ __launch_bounds__(256) void stats_finalize(const float* __restrict__ sums,
                                                      float* __restrict__ stats) {
  int i = blockIdx.x * 256 + threadIdx.x;   // 2048 = 2*B*C
  int t = i >> 10, bc = i & 1023;
  float s = sums[(t * 2 + 0) * 1024 + bc];
  float ss = sums[(t * 2 + 1) * 1024 + bc];
  float m = s * (1.0f / NN);
  float var = ss * (1.0f / NN) - m * m;
  stats[(t * 2 + 0) * 1024 + bc] = m;
  stats[(t * 2 + 1) * 1024 + bc] = rsqrtf(var + 1e-5f);
}

// ---------------- QKV: x(normed) @ W + b, then l2norm (Q,K) or V/V^2 transposed store ----------------
// LDS rows XOR-swizzled in 16B chunks: chunk' = chunk ^ (row & 7) (low 3 bits).
__global__ __launch_bounds__(256, 2) void qkv_kernel(
    const float* __restrict__ content, const float* __restrict__ style,
    const unsigned short* __restrict__ Wt,
    const float* __restrict__ bq, const float* __restrict__ bk, const float* __restrict__ bv,
    const float* __restrict__ stats,
    unsigned short* __restrict__ Qn, unsigned short* __restrict__ Kn,
    unsigned short* __restrict__ Vct) {
  __shared__ unsigned short sX[64 * 256];    // 32 KB, x-hat [row][c], swizzled (32 chunks/row)
  __shared__ unsigned short sWOT[256 * 64];  // 32 KB, sW [d][k] swizzled; V-epilogue alias sOT [d][row]
  __shared__ float sSq[64];

  int tid = threadIdx.x;
  int wid = tid >> 6, lane = tid & 63, quad = lane >> 4, l16 = lane & 15;
  int uwid = __builtin_amdgcn_readfirstlane(wid);
  int tileid = blockIdx.x;      // 0..255 over B*N/64
  int z = blockIdx.y;           // 0=Q 1=K 2=V
  int gr0 = tileid * 64;        // global row over B*N
  int b = gr0 >> 12;

  const float* X = (z == 0) ? content : style;
  int statt = (z == 0) ? 0 : 1;
  const float* mean = stats + ((statt * 2 + 0) * BB + b) * CC;
  const float* rstd = stats + ((statt * 2 + 1) * BB + b) * CC;
  bool donorm = (z < 2);

  if (tid < 64) sSq[tid] = 0.f;

  // stage x-hat tile (normalize + bf16), swizzled
  {
    int row = tid >> 2;
    int c0 = (tid & 3) * 64;
    const float* xr = X + (size_t)(gr0 + row) * CC;
    #pragma unroll
    for (int i = 0; i < 8; ++i) {
      int c = c0 + i * 8;
      f32x4 xa = *(const f32x4*)(xr + c);
      f32x4 xb = *(const f32x4*)(xr + c + 4);
      float xv[8] = {xa.x, xa.y, xa.z, xa.w, xb.x, xb.y, xb.z, xb.w};
      bf16x8 hh;
      #pragma unroll
      for (int j = 0; j < 8; ++j) {
        float x = xv[j];
        if (donorm) x = (x - mean[c + j]) * rstd[c + j];
        hh[j] = (short)f2bf(x);
      }
      int jchunk = (tid & 3) * 8 + (i ^ (row & 7));
      *(bf16x8*)(sX + row * 256 + jchunk * 8) = hh;
    }
  }

  f32x4 zero4 = {0.f, 0.f, 0.f, 0.f};
  f32x4 acc[4][4];
  #pragma unroll
  for (int i = 0; i < 4; ++i)
    #pragma unroll
    for (int j = 0; j < 4; ++j) acc[i][j] = zero4;

  int n0 = wid * 64;   // this wave's output-col base
  const unsigned short* wb = Wt + (size_t)z * 65536;

  for (int chn = 0; chn < 4; ++chn) {
    int kk0 = chn * 64;
    __syncthreads();
    // stage W chunk [256 d][64 k], swizzled (8 chunks/row)
    #pragma unroll
    for (int it = 0; it < 8; ++it) {
      int L = it * 256 + wid * 64 + lane;
      int d = L >> 3, s = L & 7;
      int j = s ^ (d & 7);
      async_cp16(wb + d * 256 + kk0 + j * 8,
                 (char*)sWOT + (size_t)(it * 256 + uwid * 64) * 16);
    }
    __syncthreads();
    #pragma unroll
    for (int ks = 0; ks < 2; ++ks) {
      bf16x8 a[4];
      #pragma unroll
      for (int mf = 0; mf < 4; ++mf) {
        int row = mf * 16 + l16;
        int j = chn * 8 + ((ks * 4 + quad) ^ (row & 7));
        a[mf] = *(const bf16x8*)(sX + row * 256 + j * 8);
      }
      #pragma unroll
      for (int nf = 0; nf < 4; ++nf) {
        int d = n0 + nf * 16 + l16;
        int j = (ks * 4 + quad) ^ (d & 7);
        bf16x8 bw = *(const bf16x8*)(sWOT + d * 64 + j * 8);
        #pragma unroll
        for (int mf = 0; mf < 4; ++mf) acc[mf][nf] = MFMA(a[mf], bw, acc[mf][nf]);
      }
    }
  }

  // bias
  const float* bias = (z == 0) ? bq : ((z == 1) ? bk : bv);
  #pragma unroll
  for (int nf = 0; nf < 4; ++nf) {
    float bb_ = bias[n0 + nf * 16 + l16];
    #pragma unroll
    for (int mf = 0; mf < 4; ++mf) {
      acc[mf][nf].x += bb_; acc[mf][nf].y += bb_;
      acc[mf][nf].z += bb_; acc[mf][nf].w += bb_;
    }
  }

  if (z < 2) {
    // l2-normalize rows, store bf16
    #pragma unroll
    for (int mf = 0; mf < 4; ++mf) {
      f32x4 ss = zero4;
      #pragma unroll
      for (int nf = 0; nf < 4; ++nf) ss += acc[mf][nf] * acc[mf][nf];
      #pragma unroll
      for (int m = 1; m < 16; m <<= 1) {
        ss.x += __shfl_xor(ss.x, m, 64);
        ss.y += __shfl_xor(ss.y, m, 64);
        ss.z += __shfl_xor(ss.z, m, 64);
        ss.w += __shfl_xor(ss.w, m, 64);
      }
      if (l16 == 0) {
        int r0 = mf * 16 + quad * 4;
        atomicAdd(&sSq[r0 + 0], ss.x);
        atomicAdd(&sSq[r0 + 1], ss.y);
        atomicAdd(&sSq[r0 + 2], ss.z);
        atomicAdd(&sSq[r0 + 3], ss.w);
      }
    }
    __syncthreads();
    if (tid < 64) sSq[tid] = rsqrtf(sSq[tid] + 1e-12f);
    __syncthreads();
    unsigned short* O = (z == 0) ? Qn : Kn;
    #pragma unroll
    for (int mf = 0; mf < 4; ++mf) {
      int r0 = mf * 16 + quad * 4;
      float rn0 = sSq[r0], rn1 = sSq[r0 + 1], rn2 = sSq[r0 + 2], rn3 = sSq[r0 + 3];
      #pragma unroll
      for (int nf = 0; nf < 4; ++nf) {
        int col = n0 + nf * 16 + l16;
        O[(size_t)(gr0 + r0 + 0) * CC + col] = f2bf(acc[mf][nf].x * rn0);
        O[(size_t)(gr0 + r0 + 1) * CC + col] = f2bf(acc[mf][nf].y * rn1);
        O[(size_t)(gr0 + r0 + 2) * CC + col] = f2bf(acc[mf][nf].z * rn2);
        O[(size_t)(gr0 + r0 + 3) * CC + col] = f2bf(acc[mf][nf].w * rn3);
      }
    }
  } else {
    // V path: stage transposed [d][row] into sOT (alias sWOT), swizzled, then global write
    __syncthreads();   // all waves done reading sWOT as sW
    #pragma unroll
    for (int mf = 0; mf < 4; ++mf) {
      int j0 = mf * 2 + (quad >> 1);
      int sub = (quad & 1) * 4;
      #pragma unroll
      for (int nf = 0; nf < 4; ++nf) {
        int col = n0 + nf * 16 + l16;
        bf16x4 pk;
        pk[0] = (short)f2bf(acc[mf][nf].x);
        pk[1] = (short)f2bf(acc[mf][nf].y);
        pk[2] = (short)f2bf(acc[mf][nf].z);
        pk[3] = (short)f2bf(acc[mf][nf].w);
        *(bf16x4*)(sWOT + col * 64 + (j0 ^ (col & 7)) * 8 + sub) = pk;
      }
    }
    __syncthreads();
    int n_in_b = gr0 & (NN - 1);
    unsigned short* vrow  = Vct + ((size_t)(b * 512 + tid)) * NN + n_in_b;
    unsigned short* v2row = Vct + ((size_t)(b * 512 + 256 + tid)) * NN + n_in_b;
    #pragma unroll
    for (int i = 0; i < 8; ++i) {
      bf16x8 hv = *(const bf16x8*)(sWOT + tid * 64 + (i ^ (tid & 7)) * 8);
      *(bf16x8*)(vrow + i * 8) = hv;
      bf16x8 h2;
      #pragma unroll
      for (int j = 0; j < 8; ++j) {
        float f = bf2f((unsigned short)hv[j]);
        h2[j] = (short)f2bf(f * f);
      }
      *(bf16x8*)(v2row + i * 8) = h2;
    }
  }
}

// ---------------- flash attention (no-max softmax; cosine logits in [-1,1]) ----------------
// 512 threads (8 waves = 2/SIMD), Q-tile 64, K-tile 64, swizzled LDS, register-prefetched PV.
__global__ __launch_bounds__(512, 2) void flash_kernel(
    const unsigned short* __restrict__ Qn,
    const unsigned short* __restrict__ Kn,
    const unsigned short* __restrict__ Vct,     // [b][512][N], ch<256: V, ch>=256: V^2
    const float* __restrict__ content,
    const float* __restrict__ stats,
    float* __restrict__ out) {
  __shared__ unsigned short sK[64 * 256];    // 32 KB [key][ch], swizzled (32 chunks/row)
  __shared__ unsigned short sVcT[512 * 64];  // 64 KB [ch][key], swizzled (8 chunks/row); epilogue: f32 sE2[256][64]
  __shared__ unsigned short sP[64 * 64];     // 8 KB  [q][key], swizzled with (q>>1)&7
  __shared__ float sL[64];

  int tid = threadIdx.x;
  int wid = tid >> 6, lane = tid & 63, quad = lane >> 4, l16 = lane & 15;
  int uwid = __builtin_amdgcn_readfirstlane(wid);

  int id = blockIdx.x;                       // XCD swizzle: batch b on XCDs {2b,2b+1}
  int b = (id >> 1) & 3;
  int tile = ((id >> 3) << 1) | (id & 1);
  int q0 = tile * 64;

  int qh = (wid & 1) * 32;         // S-phase q base (32 rows)
  int kb0 = (wid >> 1) * 16;       // S-phase key base (16 keys)
  int cw = wid * 64;               // PV ch base (64 of 512)

  if (tid < 64) sL[tid] = 0.f;

  // Q A-frags in registers: rows q0+qh+{0,16}+l16, full C=256
  bf16x8 qf[2][8];
  #pragma unroll
  for (int mf = 0; mf < 2; ++mf) {
    int row = q0 + qh + mf * 16 + l16;
    const unsigned short* base = Qn + (((size_t)b * NN + row) << 8);
    #pragma unroll
    for (int kf = 0; kf < 8; ++kf)
      qf[mf][kf] = *(const bf16x8*)(base + kf * 32 + quad * 8);
  }

  f32x4 zero4 = {0.f, 0.f, 0.f, 0.f};
  f32x4 om[4][4];
  #pragma unroll
  for (int i = 0; i < 4; ++i)
    #pragma unroll
    for (int j = 0; j < 4; ++j) om[i][j] = zero4;
  float Lr[8];
  #pragma unroll
  for (int i = 0; i < 8; ++i) Lr[i] = 0.f;

  const unsigned short* kb = Kn + (((size_t)b * NN) << 8);
  const unsigned short* vb = Vct + ((size_t)b * 512) * NN;

  // ---- stage K-tile + V-tile at key offset k0 (swizzled source indexing) ----
  auto stage = [&](int k0) {
    #pragma unroll
    for (int it = 0; it < 4; ++it) {          // sK: 64x256 shorts = 2048 chunks
      int L = it * 512 + wid * 64 + lane;
      int key = L >> 5, s = L & 31;
      int j = (s & 24) | ((s & 7) ^ (key & 7));
      async_cp16(kb + (((size_t)(k0 + key)) << 8) + j * 8,
                 (char*)sK + (size_t)(it * 512 + uwid * 64) * 16);
    }
    #pragma unroll
    for (int it = 0; it < 8; ++it) {          // sVcT: 512x64 shorts = 4096 chunks
      int L = it * 512 + wid * 64 + lane;
      int ch = L >> 3, s = L & 7;
      int j = s ^ (ch & 7);
      async_cp16(vb + (size_t)ch * NN + k0 + j * 8,
                 (char*)sVcT + (size_t)(it * 512 + uwid * 64) * 16);
    }
  };

  stage(0);
  __syncthreads();   // drain prologue staging

  int key = kb0 + l16;
  int s0chunk = key >> 3;
  int kswz = key & 7;

  for (int kt = 0; kt < 64; ++kt) {
    // ---- S = Q.K^T : wave computes D[q 32][key 16] ----
    f32x4 s0 = zero4, s1 = zero4;
    #pragma unroll
    for (int kf = 0; kf < 8; ++kf) {
      int j0 = kf * 4 + quad;
      bf16x8 bk = *(const bf16x8*)(sK + key * 256 + ((j0 & 24) | ((j0 & 7) ^ kswz)) * 8);
      s0 = MFMA(qf[0][kf], bk, s0);
      s1 = MFMA(qf[1][kf], bk, s1);
    }
    // ---- P = exp(S), accumulate L, scatter to sP (swizzled) ----
    #pragma unroll
    for (int mf = 0; mf < 2; ++mf) {
      f32x4 sv = mf ? s1 : s0;
      #pragma unroll
      for (int r = 0; r < 4; ++r) {
        int qrow = qh + mf * 16 + quad * 4 + r;
        float svr = (r == 0) ? sv.x : (r == 1) ? sv.y : (r == 2) ? sv.z : sv.w;
        float p = __expf(svr);
        Lr[mf * 4 + r] += p;
        sP[qrow * 64 + (s0chunk ^ ((qrow >> 1) & 7)) * 8 + kswz] = f2bf(p);
      }
    }
    __syncthreads();   // A: sP published, all sK reads done

    // ---- prefetch PV fragments to registers ----
    bf16x8 pf[2][4], vf[2][4];
    #pragma unroll
    for (int ks = 0; ks < 2; ++ks) {
      #pragma unroll
      for (int mf2 = 0; mf2 < 4; ++mf2) {
        int qq = mf2 * 16 + l16;
        int j = (ks * 4 + quad) ^ ((qq >> 1) & 7);
        pf[ks][mf2] = *(const bf16x8*)(sP + qq * 64 + j * 8);
      }
      #pragma unroll
      for (int nf = 0; nf < 4; ++nf) {
        int ch = cw + nf * 16 + l16;
        int j = (ks * 4 + quad) ^ (ch & 7);
        vf[ks][nf] = *(const bf16x8*)(sVcT + ch * 64 + j * 8);
      }
    }
    __syncthreads();   // B: all LDS reads done -> safe to overwrite tiles
    if (kt < 63) stage((kt + 1) * 64);   // async flies during MFMA burst

    // ---- O += P @ [V, V^2] from registers ----
    #pragma unroll
    for (int ks = 0; ks < 2; ++ks)
      #pragma unroll
      for (int nf = 0; nf < 4; ++nf)
        #pragma unroll
        for (int mf2 = 0; mf2 < 4; ++mf2)
          om[mf2][nf] = MFMA(pf[ks][mf2], vf[ks][nf], om[mf2][nf]);

    __syncthreads();   // C: drains async (compiler vmcnt(0)) -> next tiles ready
  }

  // ---- finalize L: sum over keys (l16 lanes), then over the 4 kb-waves ----
  #pragma unroll
  for (int i = 0; i < 8; ++i) {
    #pragma unroll
    for (int m = 1; m < 16; m <<= 1) Lr[i] += __shfl_xor(Lr[i], m, 64);
  }
  if (l16 == 0) {
    #pragma unroll
    for (int mf = 0; mf < 2; ++mf)
      #pragma unroll
      for (int r = 0; r < 4; ++r)
        atomicAdd(&sL[qh + mf * 16 + quad * 4 + r], Lr[mf * 4 + r]);
  }
  __syncthreads();

  // ---- epilogue: waves 4..7 dump E2 numerators to LDS (f32, swizzled 16 chunks/row) ----
  float* sE2 = (float*)sVcT;
  if (wid >= 4) {
    #pragma unroll
    for (int mf2 = 0; mf2 < 4; ++mf2) {
      int j0 = mf2 * 4 + quad;
      #pragma unroll
      for (int nf = 0; nf < 4; ++nf) {
        int ch = (wid - 4) * 64 + nf * 16 + l16;
        int j = (j0 & 8) | ((j0 & 7) ^ (ch & 7));
        *(f32x4*)(sE2 + ch * 64 + j * 4) = om[mf2][nf];
      }
    }
  }
  __syncthreads();

  if (wid < 4) {
    const float* meanc = stats + (0 * BB + b) * CC;     // content mean
    const float* rstdc = stats + (1 * BB + b) * CC;     // content rstd
    float linv[4][4];
    #pragma unroll
    for (int mf2 = 0; mf2 < 4; ++mf2)
      #pragma unroll
      for (int r = 0; r < 4; ++r)
        linv[mf2][r] = 1.0f / sL[mf2 * 16 + quad * 4 + r];
    #pragma unroll
    for (int nf = 0; nf < 4; ++nf) {
      int ch = cw + nf * 16 + l16;     // 0..255
      float mc = meanc[ch], rc = rstdc[ch];
      #pragma unroll
      for (int mf2 = 0; mf2 < 4; ++mf2) {
        int j0 = mf2 * 4 + quad;
        int j = (j0 & 8) | ((j0 & 7) ^ (ch & 7));
        f32x4 vv = *(const f32x4*)(sE2 + ch * 64 + j * 4);
        f32x4 ov = om[mf2][nf];
        #pragma unroll
        for (int r = 0; r < 4; ++r) {
          int row = mf2 * 16 + quad * 4 + r;
          float li = linv[mf2][r];
          float ovr = (r == 0) ? ov.x : (r == 1) ? ov.y : (r == 2) ? ov.z : ov.w;
          float vvr = (r == 0) ? vv.x : (r == 1) ? vv.y : (r == 2) ? vv.z : vv.w;
          float M = ovr * li;
          float E2 = vvr * li;
          float S2 = E2 - M * M;
          float S = (S2 > 0.f) ? sqrtf(S2) : 0.f;
          size_t gi = (((size_t)b * NN + q0 + row) << 8) + ch;
          float xh = (content[gi] - mc) * rc;
          out[gi] = S * xh + M;
        }
      }
    }
  }
}

// ---------------- launcher ----------------
extern "C" void kernel_launch(void* const* d_in, const int* in_sizes, int n_in,
                              void* d_out, int out_size, void* d_ws, size_t ws_size,
                              hipStream_t stream) {
  const float* content = (const float*)d_in[0];
  const float* style   = (const float*)d_in[1];
  const float* Wq = (const float*)d_in[2];
  const float* bq = (const float*)d_in[3];
  const float* Wk = (const float*)d_in[4];
  const float* bk = (const float*)d_in[5];
  const float* Wv = (const float*)d_in[6];
  const float* bv = (const float*)d_in[7];
  char* ws = (char*)d_ws;

  float* sums            = (float*)(ws + 0);                 // 16 KB
  float* stats           = (float*)(ws + 16384);             // 16 KB
  unsigned short* Wt     = (unsigned short*)(ws + 32768);    // 384 KB
  unsigned short* Qn     = (unsigned short*)(ws + 425984);   // 8 MB
  unsigned short* Kn     = (unsigned short*)(ws + 8814592);  // 8 MB
  unsigned short* Vct    = (unsigned short*)(ws + 17203200); // 16 MB
  float* outp = (float*)d_out;

  hipMemsetAsync(d_ws, 0, 16384, stream);
  hipLaunchKernelGGL(transpose_w, dim3(48), dim3(256), 0, stream, Wq, Wk, Wv, Wt);
  hipLaunchKernelGGL(stats_partial, dim3(256), dim3(256), 0, stream, content, style, sums);
  hipLaunchKernelGGL(stats_finalize, dim3(8), dim3(256), 0, stream, sums, stats);
  hipLaunchKernelGGL(qkv_kernel, dim3(256, 3), dim3(256), 0, stream,
                     content, style, Wt, bq, bk, bv, stats, Qn, Kn, Vct);
  hipLaunchKernelGGL(flash_kernel, dim3(256), dim3(512), 0, stream,
                     Qn, Kn, Vct, content, stats, outp);
}

// Round 3
// 271.100 us; speedup vs baseline: 1.5134x; 1.0796x over previous
//
#include <hip/hip_runtime.h>
#include <cstdint>

#define BB 4
#define NN 4096
#define CC 256

typedef __attribute__((ext_vector_type(8))) short bf16x8;
typedef __attribute__((ext_vector_type(4))) short bf16x4;
typedef __attribute__((ext_vector_type(4))) float f32x4;

#define MFMA(a, b, c) __builtin_amdgcn_mfma_f32_16x16x32_bf16((a), (b), (c), 0, 0, 0)

// gfx9 s_waitcnt immediate: vmcnt[3:0]+[15:14], expcnt[6:4], lgkmcnt[11:8]
#define WAITCNT(vm, xp, lgkm) (((vm) & 0xF) | (((vm) >> 4) << 14) | ((xp) << 4) | ((lgkm) << 8))

__device__ __forceinline__ unsigned short f2bf(float f) {
  union { float f; unsigned u; } v; v.f = f;
  unsigned r = v.u + 0x7fffu + ((v.u >> 16) & 1u);
  return (unsigned short)(r >> 16);
}
__device__ __forceinline__ float bf2f(unsigned short h) {
  union { unsigned u; float f; } v; v.u = ((unsigned)h) << 16;
  return v.f;
}

typedef __attribute__((address_space(3))) unsigned int lds_u32;
typedef __attribute__((address_space(1))) unsigned int glb_u32;

// async global->LDS, 16B per lane; LDS dest = wave-uniform base + lane*16
__device__ __forceinline__ void async_cp16(const void* g, void* l) {
  __builtin_amdgcn_global_load_lds((const glb_u32*)g,
                                   (lds_u32*)(unsigned)(unsigned long long)l,
                                   16, 0, 0);
}

// ---------------- W transpose: Wt[z][d][c] = W_z[c][d] as bf16 ----------------
__global__ __launch_bounds__(256) void transpose_w(const float* __restrict__ Wq,
                                                   const float* __restrict__ Wk,
                                                   const float* __restrict__ Wv,
                                                   unsigned short* __restrict__ Wt) {
  __shared__ float sT[64 * 65];
  int blk = blockIdx.x;            // 48 = 3 * 16
  int z = blk / 16, tl = blk % 16;
  int c0 = (tl >> 2) * 64, d0 = (tl & 3) * 64;
  const float* W = (z == 0) ? Wq : ((z == 1) ? Wk : Wv);
  #pragma unroll
  for (int i = 0; i < 16; ++i) {
    int e = i * 256 + threadIdx.x;
    int c = e >> 6, d = e & 63;
    sT[c * 65 + d] = W[(size_t)(c0 + c) * CC + d0 + d];
  }
  __syncthreads();
  #pragma unroll
  for (int i = 0; i < 16; ++i) {
    int e = i * 256 + threadIdx.x;
    int d = e >> 6, c = e & 63;
    Wt[(size_t)z * 65536 + (size_t)(d0 + d) * CC + c0 + c] = f2bf(sT[c * 65 + d]);
  }
}

// ---------------- instance-norm stats ----------------
__global__ __launch_bounds__(256) void stats_partial(const float* __restrict__ content,
                                                     const float* __restrict__ style,
                                                     float* __restrict__ sums) {
  int blk = blockIdx.x;                 // 1024 blocks: [t:2][b:4][chunk:128]
  int t = blk >> 9, b = (blk >> 7) & 3, chunk = blk & 127;
  const float* X = t ? style : content;
  int c = threadIdx.x;
  const float* base = X + ((size_t)b * NN + (size_t)chunk * 32) * CC + c;
  float s = 0.f, ss = 0.f;
  #pragma unroll 8
  for (int r = 0; r < 32; ++r) {
    float x = base[(size_t)r * CC];
    s += x; ss += x * x;
  }
  atomicAdd(&sums[((t * 2 + 0) * BB + b) * CC + c], s);
  atomicAdd(&sums[((t * 2 + 1) * BB + b) * CC + c], ss);
}

__global__ __launch_bounds__(256) void stats_finalize(const float* __restrict__ sums,
                                                      float* __restrict__ stats) {
  int i = blockIdx.x * 256 + threadIdx.x;   // 2048 = 2*B*C
  int t = i >> 10, bc = i & 1023;
  float s = sums[(t * 2 + 0) * 1024 + bc];
  float ss = sums[(t * 2 + 1) * 1024 + bc];
  float m = s * (1.0f / NN);
  float var = ss * (1.0f / NN) - m * m;
  stats[(t * 2 + 0) * 1024 + bc] = m;
  stats[(t * 2 + 1) * 1024 + bc] = rsqrtf(var + 1e-5f);
}

// ---------------- QKV: x(normed) @ W + b, then l2norm (Q,K) or V/V^2 transposed store ----------------
// LDS rows XOR-swizzled in 16B chunks: chunk' = chunk ^ (row & 7) (low 3 bits).
__global__ __launch_bounds__(256, 2) void qkv_kernel(
    const float* __restrict__ content, const float* __restrict__ style,
    const unsigned short* __restrict__ Wt,
    const float* __restrict__ bq, const float* __restrict__ bk, const float* __restrict__ bv,
    const float* __restrict__ stats,
    unsigned short* __restrict__ Qn, unsigned short* __restrict__ Kn,
    unsigned short* __restrict__ Vct) {
  __shared__ unsigned short sX[64 * 256];    // 32 KB, x-hat [row][c], swizzled (32 chunks/row)
  __shared__ unsigned short sWOT[256 * 64];  // 32 KB, sW [d][k] swizzled; V-epilogue alias sOT [d][row]
  __shared__ float sSq[64];

  int tid = threadIdx.x;
  int wid = tid >> 6, lane = tid & 63, quad = lane >> 4, l16 = lane & 15;
  int uwid = __builtin_amdgcn_readfirstlane(wid);
  int tileid = blockIdx.x;      // 0..255 over B*N/64
  int z = blockIdx.y;           // 0=Q 1=K 2=V
  int gr0 = tileid * 64;        // global row over B*N
  int b = gr0 >> 12;

  const float* X = (z == 0) ? content : style;
  int statt = (z == 0) ? 0 : 1;
  const float* mean = stats + ((statt * 2 + 0) * BB + b) * CC;
  const float* rstd = stats + ((statt * 2 + 1) * BB + b) * CC;
  bool donorm = (z < 2);

  if (tid < 64) sSq[tid] = 0.f;

  // stage x-hat tile (normalize + bf16), swizzled
  {
    int row = tid >> 2;
    int c0 = (tid & 3) * 64;
    const float* xr = X + (size_t)(gr0 + row) * CC;
    #pragma unroll
    for (int i = 0; i < 8; ++i) {
      int c = c0 + i * 8;
      f32x4 xa = *(const f32x4*)(xr + c);
      f32x4 xb = *(const f32x4*)(xr + c + 4);
      float xv[8] = {xa.x, xa.y, xa.z, xa.w, xb.x, xb.y, xb.z, xb.w};
      bf16x8 hh;
      #pragma unroll
      for (int j = 0; j < 8; ++j) {
        float x = xv[j];
        if (donorm) x = (x - mean[c + j]) * rstd[c + j];
        hh[j] = (short)f2bf(x);
      }
      int jchunk = (tid & 3) * 8 + (i ^ (row & 7));
      *(bf16x8*)(sX + row * 256 + jchunk * 8) = hh;
    }
  }

  f32x4 zero4 = {0.f, 0.f, 0.f, 0.f};
  f32x4 acc[4][4];
  #pragma unroll
  for (int i = 0; i < 4; ++i)
    #pragma unroll
    for (int j = 0; j < 4; ++j) acc[i][j] = zero4;

  int n0 = wid * 64;   // this wave's output-col base
  const unsigned short* wb = Wt + (size_t)z * 65536;

  for (int chn = 0; chn < 4; ++chn) {
    int kk0 = chn * 64;
    __syncthreads();
    // stage W chunk [256 d][64 k], swizzled (8 chunks/row)
    #pragma unroll
    for (int it = 0; it < 8; ++it) {
      int L = it * 256 + wid * 64 + lane;
      int d = L >> 3, s = L & 7;
      int j = s ^ (d & 7);
      async_cp16(wb + d * 256 + kk0 + j * 8,
                 (char*)sWOT + (size_t)(it * 256 + uwid * 64) * 16);
    }
    __syncthreads();
    #pragma unroll
    for (int ks = 0; ks < 2; ++ks) {
      bf16x8 a[4];
      #pragma unroll
      for (int mf = 0; mf < 4; ++mf) {
        int row = mf * 16 + l16;
        int j = chn * 8 + ((ks * 4 + quad) ^ (row & 7));
        a[mf] = *(const bf16x8*)(sX + row * 256 + j * 8);
      }
      #pragma unroll
      for (int nf = 0; nf < 4; ++nf) {
        int d = n0 + nf * 16 + l16;
        int j = (ks * 4 + quad) ^ (d & 7);
        bf16x8 bw = *(const bf16x8*)(sWOT + d * 64 + j * 8);
        #pragma unroll
        for (int mf = 0; mf < 4; ++mf) acc[mf][nf] = MFMA(a[mf], bw, acc[mf][nf]);
      }
    }
  }

  // bias
  const float* bias = (z == 0) ? bq : ((z == 1) ? bk : bv);
  #pragma unroll
  for (int nf = 0; nf < 4; ++nf) {
    float bb_ = bias[n0 + nf * 16 + l16];
    #pragma unroll
    for (int mf = 0; mf < 4; ++mf) {
      acc[mf][nf].x += bb_; acc[mf][nf].y += bb_;
      acc[mf][nf].z += bb_; acc[mf][nf].w += bb_;
    }
  }

  if (z < 2) {
    // l2-normalize rows, store bf16
    #pragma unroll
    for (int mf = 0; mf < 4; ++mf) {
      f32x4 ss = zero4;
      #pragma unroll
      for (int nf = 0; nf < 4; ++nf) ss += acc[mf][nf] * acc[mf][nf];
      #pragma unroll
      for (int m = 1; m < 16; m <<= 1) {
        ss.x += __shfl_xor(ss.x, m, 64);
        ss.y += __shfl_xor(ss.y, m, 64);
        ss.z += __shfl_xor(ss.z, m, 64);
        ss.w += __shfl_xor(ss.w, m, 64);
      }
      if (l16 == 0) {
        int r0 = mf * 16 + quad * 4;
        atomicAdd(&sSq[r0 + 0], ss.x);
        atomicAdd(&sSq[r0 + 1], ss.y);
        atomicAdd(&sSq[r0 + 2], ss.z);
        atomicAdd(&sSq[r0 + 3], ss.w);
      }
    }
    __syncthreads();
    if (tid < 64) sSq[tid] = rsqrtf(sSq[tid] + 1e-12f);
    __syncthreads();
    unsigned short* O = (z == 0) ? Qn : Kn;
    #pragma unroll
    for (int mf = 0; mf < 4; ++mf) {
      int r0 = mf * 16 + quad * 4;
      float rn0 = sSq[r0], rn1 = sSq[r0 + 1], rn2 = sSq[r0 + 2], rn3 = sSq[r0 + 3];
      #pragma unroll
      for (int nf = 0; nf < 4; ++nf) {
        int col = n0 + nf * 16 + l16;
        O[(size_t)(gr0 + r0 + 0) * CC + col] = f2bf(acc[mf][nf].x * rn0);
        O[(size_t)(gr0 + r0 + 1) * CC + col] = f2bf(acc[mf][nf].y * rn1);
        O[(size_t)(gr0 + r0 + 2) * CC + col] = f2bf(acc[mf][nf].z * rn2);
        O[(size_t)(gr0 + r0 + 3) * CC + col] = f2bf(acc[mf][nf].w * rn3);
      }
    }
  } else {
    // V path: stage transposed [d][row] into sOT (alias sWOT), swizzled, then global write
    __syncthreads();   // all waves done reading sWOT as sW
    #pragma unroll
    for (int mf = 0; mf < 4; ++mf) {
      int j0 = mf * 2 + (quad >> 1);
      int sub = (quad & 1) * 4;
      #pragma unroll
      for (int nf = 0; nf < 4; ++nf) {
        int col = n0 + nf * 16 + l16;
        bf16x4 pk;
        pk[0] = (short)f2bf(acc[mf][nf].x);
        pk[1] = (short)f2bf(acc[mf][nf].y);
        pk[2] = (short)f2bf(acc[mf][nf].z);
        pk[3] = (short)f2bf(acc[mf][nf].w);
        *(bf16x4*)(sWOT + col * 64 + (j0 ^ (col & 7)) * 8 + sub) = pk;
      }
    }
    __syncthreads();
    int n_in_b = gr0 & (NN - 1);
    unsigned short* vrow  = Vct + ((size_t)(b * 512 + tid)) * NN + n_in_b;
    unsigned short* v2row = Vct + ((size_t)(b * 512 + 256 + tid)) * NN + n_in_b;
    #pragma unroll
    for (int i = 0; i < 8; ++i) {
      bf16x8 hv = *(const bf16x8*)(sWOT + tid * 64 + (i ^ (tid & 7)) * 8);
      *(bf16x8*)(vrow + i * 8) = hv;
      bf16x8 h2;
      #pragma unroll
      for (int j = 0; j < 8; ++j) {
        float f = bf2f((unsigned short)hv[j]);
        h2[j] = (short)f2bf(f * f);
      }
      *(bf16x8*)(v2row + i * 8) = h2;
    }
  }
}

// ---------------- flash attention (no-max softmax; cosine logits in [-1,1]) ----------------
// 512 threads (8 waves), K double-buffered LDS, raw s_barrier + fine vmcnt pipeline:
// steady state per wave: 12 loads in flight (K_next=4, V_next=8); __syncthreads only
// after the K-loop (its vmcnt(0) drain is the structural ~20% stall — avoided here).
__global__ __launch_bounds__(512, 2) void flash_kernel(
    const unsigned short* __restrict__ Qn,
    const unsigned short* __restrict__ Kn,
    const unsigned short* __restrict__ Vct,     // [b][512][N], ch<256: V, ch>=256: V^2
    const float* __restrict__ content,
    const float* __restrict__ stats,
    float* __restrict__ out) {
  __shared__ unsigned short sK[2][64 * 256]; // 64 KB [buf][key][ch], swizzled (32 chunks/row)
  __shared__ unsigned short sVcT[512 * 64];  // 64 KB [ch][key], swizzled (8 chunks/row); epilogue: f32 sE2[256][64]
  __shared__ unsigned short sP[64 * 64];     // 8 KB  [q][key], swizzled with (q>>1)&7
  __shared__ float sL[64];

  int tid = threadIdx.x;
  int wid = tid >> 6, lane = tid & 63, quad = lane >> 4, l16 = lane & 15;
  int uwid = __builtin_amdgcn_readfirstlane(wid);

  int id = blockIdx.x;                       // XCD swizzle: batch b on XCDs {2b,2b+1}
  int b = (id >> 1) & 3;
  int tile = ((id >> 3) << 1) | (id & 1);
  int q0 = tile * 64;

  int qh = (wid & 1) * 32;         // S-phase q base (32 rows)
  int kb0 = (wid >> 1) * 16;       // S-phase key base (16 keys)
  int cw = wid * 64;               // PV ch base (64 of 512)

  // Q A-frags in registers: rows q0+qh+{0,16}+l16, full C=256
  bf16x8 qf[2][8];
  #pragma unroll
  for (int mf = 0; mf < 2; ++mf) {
    int row = q0 + qh + mf * 16 + l16;
    const unsigned short* base = Qn + (((size_t)b * NN + row) << 8);
    #pragma unroll
    for (int kf = 0; kf < 8; ++kf)
      qf[mf][kf] = *(const bf16x8*)(base + kf * 32 + quad * 8);
  }
  // Drain qf loads so the loop's manual vmcnt bookkeeping is exact and the
  // compiler never needs an in-loop vmcnt for qf.
  __builtin_amdgcn_s_waitcnt(WAITCNT(0, 7, 15));

  if (tid < 64) sL[tid] = 0.f;

  const unsigned short* kbp = Kn + (((size_t)b * NN) << 8);
  const unsigned short* vbp = Vct + ((size_t)b * 512) * NN;

  // stage K tile (4 loads/wave) into buf
  auto stageK = [&](int k0, int buf) {
    #pragma unroll
    for (int it = 0; it < 4; ++it) {          // 64x256 shorts = 2048 chunks
      int L = it * 512 + wid * 64 + lane;
      int key = L >> 5, s = L & 31;
      int j = (s & 24) | ((s & 7) ^ (key & 7));
      async_cp16(kbp + (((size_t)(k0 + key)) << 8) + j * 8,
                 (char*)&sK[buf][0] + (size_t)(it * 512 + uwid * 64) * 16);
    }
  };
  // stage [V;V^2] tile (8 loads/wave)
  auto stageV = [&](int k0) {
    #pragma unroll
    for (int it = 0; it < 8; ++it) {          // 512x64 shorts = 4096 chunks
      int L = it * 512 + wid * 64 + lane;
      int ch = L >> 3, s = L & 7;
      int j = s ^ (ch & 7);
      async_cp16(vbp + (size_t)ch * NN + k0 + j * 8,
                 (char*)sVcT + (size_t)(it * 512 + uwid * 64) * 16);
    }
  };

  f32x4 zero4 = {0.f, 0.f, 0.f, 0.f};
  f32x4 om[4][4];
  #pragma unroll
  for (int i = 0; i < 4; ++i)
    #pragma unroll
    for (int j = 0; j < 4; ++j) om[i][j] = zero4;
  float Lr[8];
  #pragma unroll
  for (int i = 0; i < 8; ++i) Lr[i] = 0.f;

  // prologue: K(0) then V(0) -> in-flight order matches steady state
  stageK(0, 0);
  stageV(0);

  int key = kb0 + l16;
  int s0chunk = key >> 3;
  int kswz = key & 7;

  for (int kt = 0; kt < 64; ++kt) {
    int nk0 = ((kt + 1) & 63) * 64;          // wrapped prefetch (kt=63 refetches tile 0: harmless)
    stageK(nk0, (kt + 1) & 1);
    // wait K(kt): allow 12 newest (V_kt 8 + K_next 4)
    __builtin_amdgcn_s_waitcnt(WAITCNT(12, 7, 15));
    __builtin_amdgcn_s_barrier();

    const unsigned short* sKc = &sK[kt & 1][0];
    // ---- S = Q.K^T : wave computes D[q 32][key 16] ----
    f32x4 s0 = zero4, s1 = zero4;
    #pragma unroll
    for (int kf = 0; kf < 8; ++kf) {
      int j0 = kf * 4 + quad;
      bf16x8 bk = *(const bf16x8*)(sKc + key * 256 + ((j0 & 24) | ((j0 & 7) ^ kswz)) * 8);
      s0 = MFMA(qf[0][kf], bk, s0);
      s1 = MFMA(qf[1][kf], bk, s1);
    }
    // ---- P = exp(S), accumulate L, scatter to sP (swizzled) ----
    #pragma unroll
    for (int mf = 0; mf < 2; ++mf) {
      f32x4 sv = mf ? s1 : s0;
      #pragma unroll
      for (int r = 0; r < 4; ++r) {
        int qrow = qh + mf * 16 + quad * 4 + r;
        float svr = (r == 0) ? sv.x : (r == 1) ? sv.y : (r == 2) ? sv.z : sv.w;
        float p = __expf(svr);
        Lr[mf * 4 + r] += p;
        sP[qrow * 64 + (s0chunk ^ ((qrow >> 1) & 7)) * 8 + kswz] = f2bf(p);
      }
    }
    // sP visible (lgkm 0) AND V(kt) landed: allow 4 newest (K_next only)
    __builtin_amdgcn_s_waitcnt(WAITCNT(4, 7, 0));
    __builtin_amdgcn_s_barrier();

    // ---- prefetch PV fragments to registers ----
    bf16x8 pf[2][4], vf[2][4];
    #pragma unroll
    for (int ks = 0; ks < 2; ++ks) {
      #pragma unroll
      for (int mf2 = 0; mf2 < 4; ++mf2) {
        int qq = mf2 * 16 + l16;
        int j = (ks * 4 + quad) ^ ((qq >> 1) & 7);
        pf[ks][mf2] = *(const bf16x8*)(sP + qq * 64 + j * 8);
      }
      #pragma unroll
      for (int nf = 0; nf < 4; ++nf) {
        int ch = cw + nf * 16 + l16;
        int j = (ks * 4 + quad) ^ (ch & 7);
        vf[ks][nf] = *(const bf16x8*)(sVcT + ch * 64 + j * 8);
      }
    }
    // own LDS reads complete -> after barrier everyone's are; sVcT safe to refill
    __builtin_amdgcn_s_waitcnt(WAITCNT(63, 7, 0));
    __builtin_amdgcn_s_barrier();
    stageV(nk0);   // flies during PV MFMA burst + next kt's S phase

    // ---- O += P @ [V, V^2] from registers ----
    #pragma unroll
    for (int ks = 0; ks < 2; ++ks)
      #pragma unroll
      for (int nf = 0; nf < 4; ++nf)
        #pragma unroll
        for (int mf2 = 0; mf2 < 4; ++mf2)
          om[mf2][nf] = MFMA(pf[ks][mf2], vf[ks][nf], om[mf2][nf]);
  }

  // ---- finalize L: sum over keys (l16 lanes), then over the 4 kb-waves ----
  #pragma unroll
  for (int i = 0; i < 8; ++i) {
    #pragma unroll
    for (int m = 1; m < 16; m <<= 1) Lr[i] += __shfl_xor(Lr[i], m, 64);
  }
  if (l16 == 0) {
    #pragma unroll
    for (int mf = 0; mf < 2; ++mf)
      #pragma unroll
      for (int r = 0; r < 4; ++r)
        atomicAdd(&sL[qh + mf * 16 + quad * 4 + r], Lr[mf * 4 + r]);
  }
  __syncthreads();   // full drain: dead tile-0 prefetch lands before sVcT reuse

  // ---- epilogue: waves 4..7 dump E2 numerators to LDS (f32, swizzled 16 chunks/row) ----
  float* sE2 = (float*)sVcT;
  if (wid >= 4) {
    #pragma unroll
    for (int mf2 = 0; mf2 < 4; ++mf2) {
      int j0 = mf2 * 4 + quad;
      #pragma unroll
      for (int nf = 0; nf < 4; ++nf) {
        int ch = (wid - 4) * 64 + nf * 16 + l16;
        int j = (j0 & 8) | ((j0 & 7) ^ (ch & 7));
        *(f32x4*)(sE2 + ch * 64 + j * 4) = om[mf2][nf];
      }
    }
  }
  __syncthreads();

  if (wid < 4) {
    const float* meanc = stats + (0 * BB + b) * CC;     // content mean
    const float* rstdc = stats + (1 * BB + b) * CC;     // content rstd
    float linv[4][4];
    #pragma unroll
    for (int mf2 = 0; mf2 < 4; ++mf2)
      #pragma unroll
      for (int r = 0; r < 4; ++r)
        linv[mf2][r] = 1.0f / sL[mf2 * 16 + quad * 4 + r];
    #pragma unroll
    for (int nf = 0; nf < 4; ++nf) {
      int ch = cw + nf * 16 + l16;     // 0..255
      float mc = meanc[ch], rc = rstdc[ch];
      #pragma unroll
      for (int mf2 = 0; mf2 < 4; ++mf2) {
        int j0 = mf2 * 4 + quad;
        int j = (j0 & 8) | ((j0 & 7) ^ (ch & 7));
        f32x4 vv = *(const f32x4*)(sE2 + ch * 64 + j * 4);
        f32x4 ov = om[mf2][nf];
        #pragma unroll
        for (int r = 0; r < 4; ++r) {
          int row = mf2 * 16 + quad * 4 + r;
          float li = linv[mf2][r];
          float ovr = (r == 0) ? ov.x : (r == 1) ? ov.y : (r == 2) ? ov.z : ov.w;
          float vvr = (r == 0) ? vv.x : (r == 1) ? vv.y : (r == 2) ? vv.z : vv.w;
          float M = ovr * li;
          float E2 = vvr * li;
          float S2 = E2 - M * M;
          float S = (S2 > 0.f) ? sqrtf(S2) : 0.f;
          size_t gi = (((size_t)b * NN + q0 + row) << 8) + ch;
          float xh = (content[gi] - mc) * rc;
          out[gi] = S * xh + M;
        }
      }
    }
  }
}

// ---------------- launcher ----------------
extern "C" void kernel_launch(void* const* d_in, const int* in_sizes, int n_in,
                              void* d_out, int out_size, void* d_ws, size_t ws_size,
                              hipStream_t stream) {
  const float* content = (const float*)d_in[0];
  const float* style   = (const float*)d_in[1];
  const float* Wq = (const float*)d_in[2];
  const float* bq = (const float*)d_in[3];
  const float* Wk = (const float*)d_in[4];
  const float* bk = (const float*)d_in[5];
  const float* Wv = (const float*)d_in[6];
  const float* bv = (const float*)d_in[7];
  char* ws = (char*)d_ws;

  float* sums            = (float*)(ws + 0);                 // 16 KB
  float* stats           = (float*)(ws + 16384);             // 16 KB
  unsigned short* Wt     = (unsigned short*)(ws + 32768);    // 384 KB
  unsigned short* Qn     = (unsigned short*)(ws + 425984);   // 8 MB
  unsigned short* Kn     = (unsigned short*)(ws + 8814592);  // 8 MB
  unsigned short* Vct    = (unsigned short*)(ws + 17203200); // 16 MB
  float* outp = (float*)d_out;

  hipMemsetAsync(d_ws, 0, 16384, stream);
  hipLaunchKernelGGL(transpose_w, dim3(48), dim3(256), 0, stream, Wq, Wk, Wv, Wt);
  hipLaunchKernelGGL(stats_partial, dim3(1024), dim3(256), 0, stream, content, style, sums);
  hipLaunchKernelGGL(stats_finalize, dim3(8), dim3(256), 0, stream, sums, stats);
  hipLaunchKernelGGL(qkv_kernel, dim3(256, 3), dim3(256), 0, stream,
                     content, style, Wt, bq, bk, bv, stats, Qn, Kn, Vct);
  hipLaunchKernelGGL(flash_kernel, dim3(256), dim3(512), 0, stream,
                     Qn, Kn, Vct, content, stats, outp);
}

// Round 4
// 249.396 us; speedup vs baseline: 1.6451x; 1.0870x over previous
//
#include <hip/hip_runtime.h>
#include <cstdint>

#define BB 4
#define NN 4096
#define CC 256

typedef __attribute__((ext_vector_type(8))) short bf16x8;
typedef __attribute__((ext_vector_type(4))) short bf16x4;
typedef __attribute__((ext_vector_type(4))) float f32x4;
typedef unsigned int u32;
typedef __attribute__((ext_vector_type(4))) u32 u32x4;

#define MFMA_BF16(a, b, c) __builtin_amdgcn_mfma_f32_16x16x32_bf16((a), (b), (c), 0, 0, 0)
#define MFMA_FP8(a, b, c)  __builtin_amdgcn_mfma_f32_16x16x32_fp8_fp8((a), (b), (c), 0, 0, 0)

// gfx9 s_waitcnt immediate: vmcnt[3:0]+[15:14], expcnt[6:4], lgkmcnt[11:8]
#define WAITCNT(vm, xp, lgkm) (((vm) & 0xF) | (((vm) >> 4) << 14) | ((xp) << 4) | ((lgkm) << 8))

__device__ __forceinline__ unsigned short f2bf(float f) {
  union { float f; unsigned u; } v; v.f = f;
  unsigned r = v.u + 0x7fffu + ((v.u >> 16) & 1u);
  return (unsigned short)(r >> 16);
}
__device__ __forceinline__ float bf2f(unsigned short h) {
  union { unsigned u; float f; } v; v.u = ((unsigned)h) << 16;
  return v.f;
}
// pack 4 f32 -> 4 fp8 e4m3 (OCP on gfx950) in one dword, byte order a,b,c,d
__device__ __forceinline__ u32 pk4_fp8(float a, float b, float c, float d) {
  u32 v = (u32)__builtin_amdgcn_cvt_pk_fp8_f32(a, b, 0, false);
  v = (u32)__builtin_amdgcn_cvt_pk_fp8_f32(c, d, (int)v, true);
  return v;
}

typedef __attribute__((address_space(3))) unsigned int lds_u32;
typedef __attribute__((address_space(1))) unsigned int glb_u32;

// async global->LDS, 16B per lane; LDS dest = wave-uniform base + lane*16
__device__ __forceinline__ void async_cp16(const void* g, void* l) {
  __builtin_amdgcn_global_load_lds((const glb_u32*)g,
                                   (lds_u32*)(unsigned)(unsigned long long)l,
                                   16, 0, 0);
}

// ---------------- W transpose: Wt[z][d][c] = W_z[c][d] as bf16 ----------------
__global__ __launch_bounds__(256) void transpose_w(const float* __restrict__ Wq,
                                                   const float* __restrict__ Wk,
                                                   const float* __restrict__ Wv,
                                                   unsigned short* __restrict__ Wt) {
  __shared__ float sT[64 * 65];
  int blk = blockIdx.x;            // 48 = 3 * 16
  int z = blk / 16, tl = blk % 16;
  int c0 = (tl >> 2) * 64, d0 = (tl & 3) * 64;
  const float* W = (z == 0) ? Wq : ((z == 1) ? Wk : Wv);
  #pragma unroll
  for (int i = 0; i < 16; ++i) {
    int e = i * 256 + threadIdx.x;
    int c = e >> 6, d = e & 63;
    sT[c * 65 + d] = W[(size_t)(c0 + c) * CC + d0 + d];
  }
  __syncthreads();
  #pragma unroll
  for (int i = 0; i < 16; ++i) {
    int e = i * 256 + threadIdx.x;
    int d = e >> 6, c = e & 63;
    Wt[(size_t)z * 65536 + (size_t)(d0 + d) * CC + c0 + c] = f2bf(sT[c * 65 + d]);
  }
}

// ---------------- instance-norm stats ----------------
__global__ __launch_bounds__(256) void stats_partial(const float* __restrict__ content,
                                                     const float* __restrict__ style,
                                                     float* __restrict__ sums) {
  int blk = blockIdx.x;                 // 1024 blocks: [t:2][b:4][chunk:128]
  int t = blk >> 9, b = (blk >> 7) & 3, chunk = blk & 127;
  const float* X = t ? style : content;
  int c = threadIdx.x;
  const float* base = X + ((size_t)b * NN + (size_t)chunk * 32) * CC + c;
  float s = 0.f, ss = 0.f;
  #pragma unroll 8
  for (int r = 0; r < 32; ++r) {
    float x = base[(size_t)r * CC];
    s += x; ss += x * x;
  }
  atomicAdd(&sums[((t * 2 + 0) * BB + b) * CC + c], s);
  atomicAdd(&sums[((t * 2 + 1) * BB + b) * CC + c], ss);
}

__global__ __launch_bounds__(256) void stats_finalize(const float* __restrict__ sums,
                                                      float* __restrict__ stats) {
  int i = blockIdx.x * 256 + threadIdx.x;   // 2048 = 2*B*C
  int t = i >> 10, bc = i & 1023;
  float s = sums[(t * 2 + 0) * 1024 + bc];
  float ss = sums[(t * 2 + 1) * 1024 + bc];
  float m = s * (1.0f / NN);
  float var = ss * (1.0f / NN) - m * m;
  stats[(t * 2 + 0) * 1024 + bc] = m;
  stats[(t * 2 + 1) * 1024 + bc] = rsqrtf(var + 1e-5f);
}

// ---------------- QKV: x(normed) @ W + b -> fp8 Q/K (l2norm) and fp8 V/V^2 transposed ----------------
__global__ __launch_bounds__(256, 2) void qkv_kernel(
    const float* __restrict__ content, const float* __restrict__ style,
    const unsigned short* __restrict__ Wt,
    const float* __restrict__ bq, const float* __restrict__ bk, const float* __restrict__ bv,
    const float* __restrict__ stats,
    unsigned char* __restrict__ Qn, unsigned char* __restrict__ Kn,
    unsigned char* __restrict__ Vct) {
  __shared__ unsigned short sX[64 * 256];    // 32 KB, x-hat [row][c], swizzled (32 chunks/row)
  __shared__ unsigned short sWOT[256 * 64];  // 32 KB, sW [d][k] swizzled; V-epilogue alias sOT [d][row]
  __shared__ float sSq[64];

  int tid = threadIdx.x;
  int wid = tid >> 6, lane = tid & 63, quad = lane >> 4, l16 = lane & 15;
  int uwid = __builtin_amdgcn_readfirstlane(wid);
  int tileid = blockIdx.x;      // 0..255 over B*N/64
  int z = blockIdx.y;           // 0=Q 1=K 2=V
  int gr0 = tileid * 64;        // global row over B*N
  int b = gr0 >> 12;

  const float* X = (z == 0) ? content : style;
  int statt = (z == 0) ? 0 : 1;
  const float* mean = stats + ((statt * 2 + 0) * BB + b) * CC;
  const float* rstd = stats + ((statt * 2 + 1) * BB + b) * CC;
  bool donorm = (z < 2);

  if (tid < 64) sSq[tid] = 0.f;

  // stage x-hat tile (normalize + bf16), swizzled
  {
    int row = tid >> 2;
    int c0 = (tid & 3) * 64;
    const float* xr = X + (size_t)(gr0 + row) * CC;
    #pragma unroll
    for (int i = 0; i < 8; ++i) {
      int c = c0 + i * 8;
      f32x4 xa = *(const f32x4*)(xr + c);
      f32x4 xb = *(const f32x4*)(xr + c + 4);
      float xv[8] = {xa.x, xa.y, xa.z, xa.w, xb.x, xb.y, xb.z, xb.w};
      bf16x8 hh;
      #pragma unroll
      for (int j = 0; j < 8; ++j) {
        float x = xv[j];
        if (donorm) x = (x - mean[c + j]) * rstd[c + j];
        hh[j] = (short)f2bf(x);
      }
      int jchunk = (tid & 3) * 8 + (i ^ (row & 7));
      *(bf16x8*)(sX + row * 256 + jchunk * 8) = hh;
    }
  }

  f32x4 zero4 = {0.f, 0.f, 0.f, 0.f};
  f32x4 acc[4][4];
  #pragma unroll
  for (int i = 0; i < 4; ++i)
    #pragma unroll
    for (int j = 0; j < 4; ++j) acc[i][j] = zero4;

  int n0 = wid * 64;   // this wave's output-col base
  const unsigned short* wb = Wt + (size_t)z * 65536;

  for (int chn = 0; chn < 4; ++chn) {
    int kk0 = chn * 64;
    __syncthreads();
    // stage W chunk [256 d][64 k], swizzled (8 chunks/row)
    #pragma unroll
    for (int it = 0; it < 8; ++it) {
      int L = it * 256 + wid * 64 + lane;
      int d = L >> 3, s = L & 7;
      int j = s ^ (d & 7);
      async_cp16(wb + d * 256 + kk0 + j * 8,
                 (char*)sWOT + (size_t)(it * 256 + uwid * 64) * 16);
    }
    __syncthreads();
    #pragma unroll
    for (int ks = 0; ks < 2; ++ks) {
      bf16x8 a[4];
      #pragma unroll
      for (int mf = 0; mf < 4; ++mf) {
        int row = mf * 16 + l16;
        int j = chn * 8 + ((ks * 4 + quad) ^ (row & 7));
        a[mf] = *(const bf16x8*)(sX + row * 256 + j * 8);
      }
      #pragma unroll
      for (int nf = 0; nf < 4; ++nf) {
        int d = n0 + nf * 16 + l16;
        int j = (ks * 4 + quad) ^ (d & 7);
        bf16x8 bw = *(const bf16x8*)(sWOT + d * 64 + j * 8);
        #pragma unroll
        for (int mf = 0; mf < 4; ++mf) acc[mf][nf] = MFMA_BF16(a[mf], bw, acc[mf][nf]);
      }
    }
  }

  // bias
  const float* bias = (z == 0) ? bq : ((z == 1) ? bk : bv);
  #pragma unroll
  for (int nf = 0; nf < 4; ++nf) {
    float bb_ = bias[n0 + nf * 16 + l16];
    #pragma unroll
    for (int mf = 0; mf < 4; ++mf) {
      acc[mf][nf].x += bb_; acc[mf][nf].y += bb_;
      acc[mf][nf].z += bb_; acc[mf][nf].w += bb_;
    }
  }

  if (z < 2) {
    // l2-normalize rows, store fp8
    #pragma unroll
    for (int mf = 0; mf < 4; ++mf) {
      f32x4 ss = zero4;
      #pragma unroll
      for (int nf = 0; nf < 4; ++nf) ss += acc[mf][nf] * acc[mf][nf];
      #pragma unroll
      for (int m = 1; m < 16; m <<= 1) {
        ss.x += __shfl_xor(ss.x, m, 64);
        ss.y += __shfl_xor(ss.y, m, 64);
        ss.z += __shfl_xor(ss.z, m, 64);
        ss.w += __shfl_xor(ss.w, m, 64);
      }
      if (l16 == 0) {
        int r0 = mf * 16 + quad * 4;
        atomicAdd(&sSq[r0 + 0], ss.x);
        atomicAdd(&sSq[r0 + 1], ss.y);
        atomicAdd(&sSq[r0 + 2], ss.z);
        atomicAdd(&sSq[r0 + 3], ss.w);
      }
    }
    __syncthreads();
    if (tid < 64) sSq[tid] = rsqrtf(sSq[tid] + 1e-12f);
    __syncthreads();
    unsigned char* O = (z == 0) ? Qn : Kn;
    #pragma unroll
    for (int mf = 0; mf < 4; ++mf) {
      int r0 = mf * 16 + quad * 4;
      float rn0 = sSq[r0], rn1 = sSq[r0 + 1], rn2 = sSq[r0 + 2], rn3 = sSq[r0 + 3];
      #pragma unroll
      for (int nf = 0; nf < 4; ++nf) {
        int col = n0 + nf * 16 + l16;
        u32 p01 = (u32)__builtin_amdgcn_cvt_pk_fp8_f32(acc[mf][nf].x * rn0, acc[mf][nf].y * rn1, 0, false);
        u32 p23 = (u32)__builtin_amdgcn_cvt_pk_fp8_f32(acc[mf][nf].z * rn2, acc[mf][nf].w * rn3, 0, false);
        O[(size_t)(gr0 + r0 + 0) * CC + col] = (unsigned char)(p01 & 0xff);
        O[(size_t)(gr0 + r0 + 1) * CC + col] = (unsigned char)((p01 >> 8) & 0xff);
        O[(size_t)(gr0 + r0 + 2) * CC + col] = (unsigned char)(p23 & 0xff);
        O[(size_t)(gr0 + r0 + 3) * CC + col] = (unsigned char)((p23 >> 8) & 0xff);
      }
    }
  } else {
    // V path: stage transposed [d][row] into sOT (alias sWOT), swizzled, then fp8 global write
    __syncthreads();   // all waves done reading sWOT as sW
    #pragma unroll
    for (int mf = 0; mf < 4; ++mf) {
      int j0 = mf * 2 + (quad >> 1);
      int sub = (quad & 1) * 4;
      #pragma unroll
      for (int nf = 0; nf < 4; ++nf) {
        int col = n0 + nf * 16 + l16;
        bf16x4 pk;
        pk[0] = (short)f2bf(acc[mf][nf].x);
        pk[1] = (short)f2bf(acc[mf][nf].y);
        pk[2] = (short)f2bf(acc[mf][nf].z);
        pk[3] = (short)f2bf(acc[mf][nf].w);
        *(bf16x4*)(sWOT + col * 64 + (j0 ^ (col & 7)) * 8 + sub) = pk;
      }
    }
    __syncthreads();
    int n_in_b = gr0 & (NN - 1);
    unsigned char* vrow  = Vct + ((size_t)(b * 512 + tid)) * NN + n_in_b;
    unsigned char* v2row = Vct + ((size_t)(b * 512 + 256 + tid)) * NN + n_in_b;
    #pragma unroll
    for (int i = 0; i < 4; ++i) {
      float f[16];
      #pragma unroll
      for (int g = 0; g < 2; ++g) {
        bf16x8 hv = *(const bf16x8*)(sWOT + tid * 64 + ((i * 2 + g) ^ (tid & 7)) * 8);
        #pragma unroll
        for (int j = 0; j < 8; ++j) f[g * 8 + j] = bf2f((unsigned short)hv[j]);
      }
      u32x4 v1, v2;
      v1.x = pk4_fp8(f[0], f[1], f[2], f[3]);
      v1.y = pk4_fp8(f[4], f[5], f[6], f[7]);
      v1.z = pk4_fp8(f[8], f[9], f[10], f[11]);
      v1.w = pk4_fp8(f[12], f[13], f[14], f[15]);
      v2.x = pk4_fp8(f[0]*f[0], f[1]*f[1], f[2]*f[2], f[3]*f[3]);
      v2.y = pk4_fp8(f[4]*f[4], f[5]*f[5], f[6]*f[6], f[7]*f[7]);
      v2.z = pk4_fp8(f[8]*f[8], f[9]*f[9], f[10]*f[10], f[11]*f[11]);
      v2.w = pk4_fp8(f[12]*f[12], f[13]*f[13], f[14]*f[14], f[15]*f[15]);
      *(u32x4*)(vrow + i * 16) = v1;
      *(u32x4*)(v2row + i * 16) = v2;
    }
  }
}

// ---------------- flash attention, all-fp8 datapath ----------------
// 512 threads (8 waves). K and [V;V2] double-buffered fp8 LDS tiles, prefetch
// distance 2, uniform s_waitcnt vmcnt(6) (6 loads per tile in flight).
__global__ __launch_bounds__(512, 2) void flash_kernel(
    const unsigned char* __restrict__ Qn,
    const unsigned char* __restrict__ Kn,
    const unsigned char* __restrict__ Vct,     // [b][512][N] fp8; ch<256: V, ch>=256: V^2
    const float* __restrict__ content,
    const float* __restrict__ stats,
    float* __restrict__ out) {
  // pool: sK 2x16K | sV 2x32K | sP 4K | sL 256B ; epilogue overlays f32 sE2[256][64] at base
  __shared__ __align__(16) char smem[32768 + 65536 + 4096 + 256];
  char* sKb = smem;
  char* sVb = smem + 32768;
  char* sP  = smem + 98304;
  float* sL = (float*)(smem + 102400);
  float* sE2 = (float*)smem;

  int tid = threadIdx.x;
  int wid = tid >> 6, lane = tid & 63, quad = lane >> 4, l16 = lane & 15;
  int uwid = __builtin_amdgcn_readfirstlane(wid);

  int id = blockIdx.x;                       // XCD swizzle: batch b on XCDs {2b,2b+1}
  int b = (id >> 1) & 3;
  int tile = ((id >> 3) << 1) | (id & 1);
  int q0 = tile * 64;

  int qh = (wid & 1) * 32;         // S-phase q base (32 rows)
  int kb0 = (wid >> 1) * 16;       // S-phase key base (16 keys)
  int cw = wid * 64;               // PV ch base (64 of 512)

  // Q A-frags fp8 in registers: rows q0+qh+{0,16}+l16, full C=256
  long qf[2][8];
  #pragma unroll
  for (int mf = 0; mf < 2; ++mf) {
    int row = q0 + qh + mf * 16 + l16;
    const unsigned char* base = Qn + (((size_t)b * NN + row) << 8);
    #pragma unroll
    for (int kf = 0; kf < 8; ++kf)
      qf[mf][kf] = *(const long*)(base + kf * 32 + quad * 8);
  }
  __builtin_amdgcn_s_waitcnt(WAITCNT(0, 7, 15));   // drain qf: loop vmcnt counts staging only

  if (tid < 64) sL[tid] = 0.f;

  const unsigned char* kbp = Kn + (((size_t)b * NN) << 8);
  const unsigned char* vbp = Vct + ((size_t)b * 512) * NN;

  // K tile [64 key][256 c] fp8 = 16 KB; 16B chunks swizzled: slot = c16 ^ (key&15)
  auto stageK = [&](int k0, int buf) {
    char* dst = sKb + buf * 16384;
    #pragma unroll
    for (int it = 0; it < 2; ++it) {
      int L = it * 512 + wid * 64 + lane;
      int ky = L >> 4, s = L & 15;
      int c16 = s ^ (ky & 15);
      async_cp16(kbp + (((size_t)(k0 + ky)) << 8) + c16 * 16,
                 dst + (size_t)(it * 512 + uwid * 64) * 16);
    }
  };
  // [V;V2] tile [512 ch][64 key] fp8 = 32 KB; 128B row-pairs, slot8 = ((ch&1)*4+c16) ^ ((ch>>1)&7)
  auto stageV = [&](int k0, int buf) {
    char* dst = sVb + buf * 32768;
    #pragma unroll
    for (int it = 0; it < 4; ++it) {
      int L = it * 512 + wid * 64 + lane;
      int r128 = L >> 3, s8 = L & 7;
      int x = s8 ^ (r128 & 7);
      int ch = (r128 << 1) | (x >> 2);
      int k16 = x & 3;
      async_cp16(vbp + (size_t)ch * NN + k0 + k16 * 16,
                 dst + (size_t)(it * 512 + uwid * 64) * 16);
    }
  };

  f32x4 zero4 = {0.f, 0.f, 0.f, 0.f};
  f32x4 om[4][4];
  #pragma unroll
  for (int i = 0; i < 4; ++i)
    #pragma unroll
    for (int j = 0; j < 4; ++j) om[i][j] = zero4;
  float Lr[8];
  #pragma unroll
  for (int i = 0; i < 8; ++i) Lr[i] = 0.f;

  // prologue: tiles 0 and 1 (6 loads each)
  stageK(0, 0);  stageV(0, 0);
  stageK(64, 1); stageV(64, 1);

  int keyrow = (kb0 + l16) * 256;
  int key15 = l16;                  // (kb0+l16)&15
  int khalf = (quad & 1) * 8;

  for (int kt = 0; kt < 64; ++kt) {
    // tile kt ready (6 newer = tile kt+1 in flight)
    __builtin_amdgcn_s_waitcnt(WAITCNT(6, 7, 15));
    __builtin_amdgcn_s_barrier();

    const char* sKc = sKb + (kt & 1) * 16384;
    // ---- S = Q.K^T : wave computes D[q 32][key 16], fp8 MFMA ----
    f32x4 s0 = zero4, s1 = zero4;
    #pragma unroll
    for (int kf = 0; kf < 8; ++kf) {
      int slot = (kf * 2 + (quad >> 1)) ^ key15;
      long bk = *(const long*)(sKc + keyrow + slot * 16 + khalf);
      s0 = MFMA_FP8(qf[0][kf], bk, s0);
      s1 = MFMA_FP8(qf[1][kf], bk, s1);
    }
    // ---- P = exp(S), accumulate L, fp8 scatter to sP ----
    #pragma unroll
    for (int mf = 0; mf < 2; ++mf) {
      f32x4 sv = mf ? s1 : s0;
      float p0 = __expf(sv.x), p1 = __expf(sv.y), p2 = __expf(sv.z), p3 = __expf(sv.w);
      Lr[mf * 4 + 0] += p0; Lr[mf * 4 + 1] += p1;
      Lr[mf * 4 + 2] += p2; Lr[mf * 4 + 3] += p3;
      u32 b01 = (u32)__builtin_amdgcn_cvt_pk_fp8_f32(p0, p1, 0, false);
      u32 b23 = (u32)__builtin_amdgcn_cvt_pk_fp8_f32(p2, p3, 0, false);
      int qbase = qh + mf * 16 + quad * 4;
      #pragma unroll
      for (int r = 0; r < 4; ++r) {
        int q = qbase + r;
        u32 byte = (r < 2) ? ((r == 0) ? (b01 & 0xff) : ((b01 >> 8) & 0xff))
                           : ((r == 2) ? (b23 & 0xff) : ((b23 >> 8) & 0xff));
        int addr = (q >> 1) * 128 + ((((q & 1) * 4 + (wid >> 1))) ^ ((q >> 1) & 7)) * 16 + l16;
        sP[addr] = (unsigned char)byte;
      }
    }
    __builtin_amdgcn_s_waitcnt(WAITCNT(63, 7, 0));   // sP visible; own sK reads retired
    __builtin_amdgcn_s_barrier();

    // ---- prefetch PV fragments (fp8) to registers ----
    const char* sVc = sVb + (kt & 1) * 32768;
    long pf[2][4], vf[2][4];
    #pragma unroll
    for (int ks = 0; ks < 2; ++ks) {
      int c16 = ks * 2 + (quad >> 1);
      #pragma unroll
      for (int mf2 = 0; mf2 < 4; ++mf2) {
        int q = mf2 * 16 + l16;
        pf[ks][mf2] = *(const long*)(sP + (q >> 1) * 128 +
                        (((q & 1) * 4 + c16) ^ ((q >> 1) & 7)) * 16 + khalf);
      }
      #pragma unroll
      for (int nf = 0; nf < 4; ++nf) {
        int ch = cw + nf * 16 + l16;
        vf[ks][nf] = *(const long*)(sVc + (ch >> 1) * 128 +
                        (((ch & 1) * 4 + c16) ^ ((ch >> 1) & 7)) * 16 + khalf);
      }
    }
    __builtin_amdgcn_s_waitcnt(WAITCNT(63, 7, 0));   // all own LDS reads retired
    __builtin_amdgcn_s_barrier();                    // -> everyone's reads done, bufs reusable

    int nk = ((kt + 2) & 63) * 64;   // wrapped (kt>=62 refetches tiles 0/1: harmless)
    stageK(nk, kt & 1);
    stageV(nk, kt & 1);

    // ---- O += P @ [V, V^2] from registers ----
    #pragma unroll
    for (int ks = 0; ks < 2; ++ks)
      #pragma unroll
      for (int nf = 0; nf < 4; ++nf)
        #pragma unroll
        for (int mf2 = 0; mf2 < 4; ++mf2)
          om[mf2][nf] = MFMA_FP8(pf[ks][mf2], vf[ks][nf], om[mf2][nf]);
  }

  // ---- finalize L: sum over keys (l16 lanes), then over the 4 kb-waves ----
  #pragma unroll
  for (int i = 0; i < 8; ++i) {
    #pragma unroll
    for (int m = 1; m < 16; m <<= 1) Lr[i] += __shfl_xor(Lr[i], m, 64);
  }
  if (l16 == 0) {
    #pragma unroll
    for (int mf = 0; mf < 2; ++mf)
      #pragma unroll
      for (int r = 0; r < 4; ++r)
        atomicAdd(&sL[qh + mf * 16 + quad * 4 + r], Lr[mf * 4 + r]);
  }
  // drain dead prefetch DMA + make sL visible before overlaying sE2 on sK/sV
  __builtin_amdgcn_s_waitcnt(WAITCNT(0, 7, 0));
  __builtin_amdgcn_s_barrier();

  // ---- epilogue: waves 4..7 dump E2 numerators to LDS (f32 [256][64], 16-chunk swizzle) ----
  if (wid >= 4) {
    #pragma unroll
    for (int mf2 = 0; mf2 < 4; ++mf2) {
      #pragma unroll
      for (int nf = 0; nf < 4; ++nf) {
        int ch = (wid - 4) * 64 + nf * 16 + l16;
        int cidx = (mf2 * 4 + quad) ^ (ch & 15);
        *(f32x4*)(sE2 + ch * 64 + cidx * 4) = om[mf2][nf];
      }
    }
  }
  __syncthreads();

  if (wid < 4) {
    const float* meanc = stats + (0 * BB + b) * CC;     // content mean
    const float* rstdc = stats + (1 * BB + b) * CC;     // content rstd
    float linv[4][4];
    #pragma unroll
    for (int mf2 = 0; mf2 < 4; ++mf2)
      #pragma unroll
      for (int r = 0; r < 4; ++r)
        linv[mf2][r] = 1.0f / sL[mf2 * 16 + quad * 4 + r];
    #pragma unroll
    for (int nf = 0; nf < 4; ++nf) {
      int ch = cw + nf * 16 + l16;     // 0..255
      float mc = meanc[ch], rc = rstdc[ch];
      #pragma unroll
      for (int mf2 = 0; mf2 < 4; ++mf2) {
        int cidx = (mf2 * 4 + quad) ^ (ch & 15);
        f32x4 vv = *(const f32x4*)(sE2 + ch * 64 + cidx * 4);
        f32x4 ov = om[mf2][nf];
        #pragma unroll
        for (int r = 0; r < 4; ++r) {
          int row = mf2 * 16 + quad * 4 + r;
          float li = linv[mf2][r];
          float ovr = (r == 0) ? ov.x : (r == 1) ? ov.y : (r == 2) ? ov.z : ov.w;
          float vvr = (r == 0) ? vv.x : (r == 1) ? vv.y : (r == 2) ? vv.z : vv.w;
          float M = ovr * li;
          float E2 = vvr * li;
          float S2 = E2 - M * M;
          float S = (S2 > 0.f) ? sqrtf(S2) : 0.f;
          size_t gi = (((size_t)b * NN + q0 + row) << 8) + ch;
          float xh = (content[gi] - mc) * rc;
          out[gi] = S * xh + M;
        }
      }
    }
  }
}

// ---------------- launcher ----------------
extern "C" void kernel_launch(void* const* d_in, const int* in_sizes, int n_in,
                              void* d_out, int out_size, void* d_ws, size_t ws_size,
                              hipStream_t stream) {
  const float* content = (const float*)d_in[0];
  const float* style   = (const float*)d_in[1];
  const float* Wq = (const float*)d_in[2];
  const float* bq = (const float*)d_in[3];
  const float* Wk = (const float*)d_in[4];
  const float* bk = (const float*)d_in[5];
  const float* Wv = (const float*)d_in[6];
  const float* bv = (const float*)d_in[7];
  char* ws = (char*)d_ws;

  float* sums        = (float*)(ws + 0);                 // 16 KB
  float* stats       = (float*)(ws + 16384);             // 16 KB
  unsigned short* Wt = (unsigned short*)(ws + 32768);    // 384 KB
  unsigned char* Qn  = (unsigned char*)(ws + 425984);    // 4 MB fp8
  unsigned char* Kn  = (unsigned char*)(ws + 4620288);   // 4 MB fp8
  unsigned char* Vct = (unsigned char*)(ws + 8814592);   // 8 MB fp8 [b][512][N]
  float* outp = (float*)d_out;

  hipMemsetAsync(d_ws, 0, 16384, stream);
  hipLaunchKernelGGL(transpose_w, dim3(48), dim3(256), 0, stream, Wq, Wk, Wv, Wt);
  hipLaunchKernelGGL(stats_partial, dim3(1024), dim3(256), 0, stream, content, style, sums);
  hipLaunchKernelGGL(stats_finalize, dim3(8), dim3(256), 0, stream, sums, stats);
  hipLaunchKernelGGL(qkv_kernel, dim3(256, 3), dim3(256), 0, stream,
                     content, style, Wt, bq, bk, bv, stats, Qn, Kn, Vct);
  hipLaunchKernelGGL(flash_kernel, dim3(256), dim3(512), 0, stream,
                     Qn, Kn, Vct, content, stats, outp);
}